// Round 1
// baseline (913.863 us; speedup 1.0000x reference)
//
#include <hip/hip_runtime.h>
#include <cstdint>
#include <cstddef>

// NUFFT type-2, torchkbnufft-compatible (J=6, alpha=14.04, os=2).
// Pipeline per phase p (5 phases, 16 coil-images each, 320x320 -> 640x640):
//   stageA: apodize+pad rows, FFT-640 along W  -> A[i][h][kw]   (rows contiguous)
//   stageB: FFT-640 along H (pad 320->640)     -> G[i][kw][kh]  (transposed, contiguous writes)
//   interp: 6x6 KB taps gather + phase         -> out[(p*16+i)*16000+l]
// FFT-640 = Stockham, radix-5 then 7x radix-2, one wave (64 lanes) per line,
// LDS ping-pong 2x640 complex per wave (40KB per 4-wave block).

#define PI_F     3.14159265358979323846f
#define KB_ALPHA 14.04f
#define NPH  5
#define NIMG 16
#define NH   320
#define NK   640
#define KLEN 16000

// ---- modified Bessel I0 (A&S 9.8.1 / 9.8.2, rel err ~2e-7). I0(alpha) cancels
// between apodization (numerator) and tap weights (denominator), so only the
// ratio accuracy matters. ----
__device__ __forceinline__ float i0f(float x) {
  if (x < 3.75f) {
    float t = x * (1.0f / 3.75f), t2 = t * t;
    return 1.0f + t2 * (3.5156229f + t2 * (3.0899424f + t2 * (1.2067492f +
                 t2 * (0.2659732f + t2 * (0.0360768f + t2 * 0.0045813f)))));
  }
  float t = 3.75f / x;
  float poly = 0.39894228f + t * (0.01328592f + t * (0.00225319f + t * (-0.00157565f +
               t * (0.00916281f + t * (-0.02057706f + t * (0.02635537f +
               t * (-0.01647633f + t * 0.00392377f)))))));
  return expf(x) * rsqrtf(x) * poly;
}

// apodization scale (1/FT(KB)); z^2 = alpha^2-(pi*J*u)^2 > 0 always for |u|<=0.25
__device__ __forceinline__ float apodf(int n) {
  float u = (float)(n - 160) * (1.0f / 640.0f);
  float pj = PI_F * 6.0f * u;
  float z = sqrtf(KB_ALPHA * KB_ALPHA - pj * pj);
  float sh = 0.5f * (expf(z) - expf(-z));     // sinh(z)
  return z * i0f(KB_ALPHA) / (6.0f * sh);     // 1/ft = z*I0a/(J*sinh z)
}

__device__ __forceinline__ float2 cxmad(float2 a, float2 w, float2 x) {
  a.x = fmaf(w.x, x.x, fmaf(-w.y, x.y, a.x));
  a.y = fmaf(w.x, x.y, fmaf( w.y, x.x, a.y));
  return a;
}

// ---- Stockham radix-2 stage, subtransform size P -> 2P, 320 butterflies/wave ----
template <int P>
__device__ __forceinline__ void radix2_stage(const float2* __restrict__ src,
                                             float2* __restrict__ dst, int lane) {
#pragma unroll
  for (int s = 0; s < 5; s++) {
    int t = lane + 64 * s;
    int k = t % P, b = t / P;
    float2 u = src[t], v = src[t + 320];
    float sn, cs;
    __sincosf(-(PI_F / (float)P) * (float)k, &sn, &cs);  // W_{2P}^k
    float2 tv = make_float2(fmaf(cs, v.x, -sn * v.y), fmaf(cs, v.y, sn * v.x));
    dst[b * 2 * P + k]     = make_float2(u.x + tv.x, u.y + tv.y);
    dst[b * 2 * P + k + P] = make_float2(u.x - tv.x, u.y - tv.y);
  }
  __syncthreads();
}

// forward FFT, N=640, input in b0, output ends in b0 (8 stages, even ping-pong)
__device__ void fft640(float2* b0, float2* b1, int lane) {
  __syncthreads();
  const float2 w51 = make_float2( 0.309016994374947424f, -0.951056516295153572f);
  const float2 w52 = make_float2(-0.809016994374947424f, -0.587785252292473129f);
  const float2 w53 = make_float2(-0.809016994374947424f,  0.587785252292473129f);
  const float2 w54 = make_float2( 0.309016994374947424f,  0.951056516295153572f);
  // radix-5 DIT first stage (p=1, no twiddles): 128 groups, 2 per lane
#pragma unroll
  for (int s = 0; s < 2; s++) {
    int t = lane + 64 * s;
    float2 x0 = b0[t], x1 = b0[t + 128], x2 = b0[t + 256], x3 = b0[t + 384], x4 = b0[t + 512];
    float2 z0 = make_float2(x0.x + x1.x + x2.x + x3.x + x4.x,
                            x0.y + x1.y + x2.y + x3.y + x4.y);
    float2 z1 = x0; z1 = cxmad(z1, w51, x1); z1 = cxmad(z1, w52, x2); z1 = cxmad(z1, w53, x3); z1 = cxmad(z1, w54, x4);
    float2 z2 = x0; z2 = cxmad(z2, w52, x1); z2 = cxmad(z2, w54, x2); z2 = cxmad(z2, w51, x3); z2 = cxmad(z2, w53, x4);
    float2 z3 = x0; z3 = cxmad(z3, w53, x1); z3 = cxmad(z3, w51, x2); z3 = cxmad(z3, w54, x3); z3 = cxmad(z3, w52, x4);
    float2 z4 = x0; z4 = cxmad(z4, w54, x1); z4 = cxmad(z4, w53, x2); z4 = cxmad(z4, w52, x3); z4 = cxmad(z4, w51, x4);
    b1[5 * t] = z0; b1[5 * t + 1] = z1; b1[5 * t + 2] = z2; b1[5 * t + 3] = z3; b1[5 * t + 4] = z4;
  }
  __syncthreads();
  radix2_stage<5>  (b1, b0, lane);
  radix2_stage<10> (b0, b1, lane);
  radix2_stage<20> (b1, b0, lane);
  radix2_stage<40> (b0, b1, lane);
  radix2_stage<80> (b1, b0, lane);
  radix2_stage<160>(b0, b1, lane);
  radix2_stage<320>(b1, b0, lane);
}

// ---- stage A: row FFTs. grid = chunk*16*80 blocks, 1 wave = 1 row ----
__global__ __launch_bounds__(256) void stageA_kernel(const float* __restrict__ img,
                                                     float* __restrict__ A, int p0) {
  __shared__ float2 lds[4][2][NK];
  int wv = threadIdx.x >> 6, lane = threadIdx.x & 63;
  int bx = blockIdx.x;
  int pp = bx / (NIMG * 80);
  int rem = bx - pp * (NIMG * 80);
  int i = rem / 80, hg = rem - i * 80;
  int h = hg * 4 + wv;
  int p = p0 + pp;
  const float2* src = (const float2*)img + ((size_t)(p * NIMG + i) * NH + h) * NH;
  float2* b0 = lds[wv][0];
  float2* b1 = lds[wv][1];
  float ah = apodf(h) * (1.0f / 640.0f);  // fold 1/sqrt(Kh*Kw) ortho norm
#pragma unroll
  for (int s = 0; s < 5; s++) {
    int w = lane + 64 * s;
    float2 v = src[w];
    float sc = apodf(w) * ah;
    b0[w] = make_float2(v.x * sc, v.y * sc);
    b0[w + 320] = make_float2(0.f, 0.f);
  }
  fft640(b0, b1, lane);
  float2* dst = (float2*)A + ((size_t)(pp * NIMG + i) * NH + h) * NK;
#pragma unroll
  for (int s = 0; s < 10; s++) {
    int kw = lane + 64 * s;
    dst[kw] = b0[kw];
  }
}

// ---- stage B: column FFTs. grid = chunk*16*160 blocks, 1 wave = 1 column ----
__global__ __launch_bounds__(256) void stageB_kernel(const float* __restrict__ A,
                                                     float* __restrict__ G) {
  __shared__ float2 lds[4][2][NK];
  int wv = threadIdx.x >> 6, lane = threadIdx.x & 63;
  int bx = blockIdx.x;
  int pi = bx / 160;                 // pp*NIMG + i
  int kwg = bx - pi * 160;
  int kw = kwg * 4 + wv;
  const float2* col = (const float2*)A + (size_t)pi * NH * NK + kw;
  float2* b0 = lds[wv][0];
  float2* b1 = lds[wv][1];
#pragma unroll
  for (int s = 0; s < 5; s++) {
    int h = lane + 64 * s;
    b0[h] = col[(size_t)h * NK];     // strided 8B; 4 adjacent kw share 64B lines via L1/L2
    b0[h + 320] = make_float2(0.f, 0.f);
  }
  fft640(b0, b1, lane);
  float2* dst = (float2*)G + ((size_t)pi * NK + kw) * NK;  // transposed: kh contiguous
#pragma unroll
  for (int s = 0; s < 10; s++) {
    int kh = lane + 64 * s;
    dst[kh] = b0[kh];
  }
}

// ---- taps: per (phase, point): 6 weights+indices per dim + recentering phase ----
__global__ __launch_bounds__(256) void taps_kernel(const float* __restrict__ traj,
                                                   float* __restrict__ tapw,
                                                   int* __restrict__ tapi) {
  int t = blockIdx.x * 256 + threadIdx.x;
  if (t >= NPH * KLEN) return;
  int p = t / KLEN, l = t - p * KLEN;
  float inv_i0a = 1.0f / i0f(KB_ALPHA);
  float* wout = tapw + (size_t)t * 14;
  int* iout = tapi + (size_t)t * 12;
  float ang = 0.0f;
#pragma unroll
  for (int d = 0; d < 2; d++) {
    float om = traj[((size_t)p * 2 + d) * KLEN + l];
    float tt = om * 640.0f / 6.28318530717958647692f;
    float base = floorf(tt - 3.0f);
    ang += om * 160.0f;              // n_shift = 320//2
#pragma unroll
    for (int j = 0; j < 6; j++) {
      float kf = base + (float)(j + 1);
      float u = tt - kf;
      float arg = fmaxf(1.0f - (u * u) * (1.0f / 9.0f), 0.0f);
      wout[d * 6 + j] = i0f(KB_ALPHA * sqrtf(arg)) * inv_i0a;
      int ki = (int)kf + 640;        // kf in [-323,636] -> ki in [317,1276]
      if (ki >= 640) ki -= 640;
      iout[d * 6 + j] = ki;
    }
  }
  float s, c;
  sincosf(ang, &s, &c);              // accurate path: |ang| up to ~1005 rad
  wout[12] = c;
  wout[13] = s;
}

// ---- interp: thread = (image i, point l); 36 float2 gathers from G (L2/L3 hot) ----
__global__ __launch_bounds__(256) void interp_kernel(const float* __restrict__ G,
                                                     const float* __restrict__ tapw,
                                                     const int* __restrict__ tapi,
                                                     float* __restrict__ out, int p0) {
  int pp = blockIdx.x / 1000;
  int rem = blockIdx.x - pp * 1000;
  int t = rem * 256 + threadIdx.x;   // 0..255999
  int i = t / KLEN;
  int l = t - i * KLEN;
  int p = p0 + pp;
  const float* w = tapw + (size_t)(p * KLEN + l) * 14;
  const int* ix = tapi + (size_t)(p * KLEN + l) * 12;
  const float2* g = (const float2*)G + (size_t)(pp * NIMG + i) * NK * NK;
  float whv[6]; int ihv[6];
#pragma unroll
  for (int j = 0; j < 6; j++) { whv[j] = w[j]; ihv[j] = ix[j]; }
  float ar = 0.f, ai = 0.f;
#pragma unroll
  for (int jw = 0; jw < 6; jw++) {
    const float2* col = g + (size_t)ix[6 + jw] * NK;
    float sr = 0.f, si = 0.f;
#pragma unroll
    for (int jh = 0; jh < 6; jh++) {
      float2 v = col[ihv[jh]];
      sr = fmaf(whv[jh], v.x, sr);
      si = fmaf(whv[jh], v.y, si);
    }
    float wwj = w[6 + jw];
    ar = fmaf(wwj, sr, ar);
    ai = fmaf(wwj, si, ai);
  }
  float c = w[12], s = w[13];
  size_t o = ((size_t)(p * NIMG + i) * KLEN + l) * 2;
  out[o]     = ar * c - ai * s;
  out[o + 1] = ar * s + ai * c;
}

extern "C" void kernel_launch(void* const* d_in, const int* in_sizes, int n_in,
                              void* d_out, int out_size, void* d_ws, size_t ws_size,
                              hipStream_t stream) {
  const float* img  = (const float*)d_in[0];   // (1,5,8,2,320,320,2) f32
  const float* traj = (const float*)d_in[1];   // (5,2,16000) f32
  float* out = (float*)d_out;                  // (1,5,8,2,16000,2) f32

  char* ws = (char*)d_ws;
  float* tapw = (float*)ws;                               // 5*16000*14*4 = 4,480,000 B
  int*   tapi = (int*)(ws + 4480000);                     // 5*16000*12*4 = 3,840,000 B
  char*  heap = ws + 8320000;
  const size_t Ab = (size_t)NIMG * NH * NK * 2 * 4;       // 26,214,400 B / phase
  const size_t Gb = (size_t)NIMG * NK * NK * 2 * 4;       // 52,428,800 B / phase
  // all-phases layout if workspace allows (fewer launches), else per-phase loop
  int chunk = (ws_size >= (size_t)8320000 + 5 * (Ab + Gb)) ? 5 : 1;
  float* A = (float*)heap;
  float* G = (float*)(heap + (size_t)chunk * Ab);

  taps_kernel<<<(NPH * KLEN + 255) / 256, 256, 0, stream>>>(traj, tapw, tapi);
  for (int p0 = 0; p0 < NPH; p0 += chunk) {
    stageA_kernel<<<chunk * NIMG * 80, 256, 0, stream>>>(img, A, p0);
    stageB_kernel<<<chunk * NIMG * 160, 256, 0, stream>>>(A, G);
    interp_kernel<<<chunk * 1000, 256, 0, stream>>>(G, tapw, tapi, out, p0);
  }
}

// Round 2
// 747.116 us; speedup vs baseline: 1.2232x; 1.2232x over previous
//
#include <hip/hip_runtime.h>
#include <cstdint>
#include <cstddef>

// NUFFT type-2, torchkbnufft-compatible (J=6, alpha=14.04, os=2).
// Pipeline per phase p (5 phases, 16 coil-images each, 320x320 -> 640x640):
//   stageA: apodize+pad rows, FFT-640 along W  -> A_T[i][kw][h]  (TRANSPOSED write)
//   stageB: FFT-640 along H (pad 320->640)     -> G[i][kw][kh]   (contiguous read+write)
//   interp: 6x6 KB taps gather + phase, XCD-pinned so each image (3.27MB) stays in
//           one XCD's 4MB L2                    -> out[(p*16+i)*16000+l]
// FFT-640 = Stockham, radix-5 then 7x radix-2, one wave (64 lanes) per line,
// LDS ping-pong 2x644 complex per wave (padded stride 644: transpose read 2-way free).

#define PI_F     3.14159265358979323846f
#define KB_ALPHA 14.04f
#define NPH  5
#define NIMG 16
#define NH   320
#define NK   640
#define KLEN 16000
#define LSTR 644   // padded LDS line stride (float2 elems)

// ---- modified Bessel I0 (A&S 9.8.1 / 9.8.2, rel err ~2e-7). I0(alpha) cancels
// between apodization (numerator) and tap weights (denominator). ----
__device__ __forceinline__ float i0f(float x) {
  if (x < 3.75f) {
    float t = x * (1.0f / 3.75f), t2 = t * t;
    return 1.0f + t2 * (3.5156229f + t2 * (3.0899424f + t2 * (1.2067492f +
                 t2 * (0.2659732f + t2 * (0.0360768f + t2 * 0.0045813f)))));
  }
  float t = 3.75f / x;
  float poly = 0.39894228f + t * (0.01328592f + t * (0.00225319f + t * (-0.00157565f +
               t * (0.00916281f + t * (-0.02057706f + t * (0.02635537f +
               t * (-0.01647633f + t * 0.00392377f)))))));
  return expf(x) * rsqrtf(x) * poly;
}

// apodization scale (1/FT(KB)); z^2 = alpha^2-(pi*J*u)^2 > 0 always for |u|<=0.25
__device__ __forceinline__ float apodf(int n) {
  float u = (float)(n - 160) * (1.0f / 640.0f);
  float pj = PI_F * 6.0f * u;
  float z = sqrtf(KB_ALPHA * KB_ALPHA - pj * pj);
  float sh = 0.5f * (expf(z) - expf(-z));     // sinh(z)
  return z * i0f(KB_ALPHA) / (6.0f * sh);     // 1/ft = z*I0a/(J*sinh z)
}

__device__ __forceinline__ float2 cxmad(float2 a, float2 w, float2 x) {
  a.x = fmaf(w.x, x.x, fmaf(-w.y, x.y, a.x));
  a.y = fmaf(w.x, x.y, fmaf( w.y, x.x, a.y));
  return a;
}

// ---- Stockham radix-2 stage, subtransform size P -> 2P, 320 butterflies/wave ----
template <int P>
__device__ __forceinline__ void radix2_stage(const float2* __restrict__ src,
                                             float2* __restrict__ dst, int lane) {
#pragma unroll
  for (int s = 0; s < 5; s++) {
    int t = lane + 64 * s;
    int k = t % P, b = t / P;
    float2 u = src[t], v = src[t + 320];
    float sn, cs;
    __sincosf(-(PI_F / (float)P) * (float)k, &sn, &cs);  // W_{2P}^k
    float2 tv = make_float2(fmaf(cs, v.x, -sn * v.y), fmaf(cs, v.y, sn * v.x));
    dst[b * 2 * P + k]     = make_float2(u.x + tv.x, u.y + tv.y);
    dst[b * 2 * P + k + P] = make_float2(u.x - tv.x, u.y - tv.y);
  }
  __syncthreads();
}

// forward FFT, N=640, input in b0, output ends in b0 (8 stages, even ping-pong)
__device__ void fft640(float2* b0, float2* b1, int lane) {
  __syncthreads();
  const float2 w51 = make_float2( 0.309016994374947424f, -0.951056516295153572f);
  const float2 w52 = make_float2(-0.809016994374947424f, -0.587785252292473129f);
  const float2 w53 = make_float2(-0.809016994374947424f,  0.587785252292473129f);
  const float2 w54 = make_float2( 0.309016994374947424f,  0.951056516295153572f);
  // radix-5 DIT first stage (p=1, no twiddles): 128 groups, 2 per lane
#pragma unroll
  for (int s = 0; s < 2; s++) {
    int t = lane + 64 * s;
    float2 x0 = b0[t], x1 = b0[t + 128], x2 = b0[t + 256], x3 = b0[t + 384], x4 = b0[t + 512];
    float2 z0 = make_float2(x0.x + x1.x + x2.x + x3.x + x4.x,
                            x0.y + x1.y + x2.y + x3.y + x4.y);
    float2 z1 = x0; z1 = cxmad(z1, w51, x1); z1 = cxmad(z1, w52, x2); z1 = cxmad(z1, w53, x3); z1 = cxmad(z1, w54, x4);
    float2 z2 = x0; z2 = cxmad(z2, w52, x1); z2 = cxmad(z2, w54, x2); z2 = cxmad(z2, w51, x3); z2 = cxmad(z2, w53, x4);
    float2 z3 = x0; z3 = cxmad(z3, w53, x1); z3 = cxmad(z3, w51, x2); z3 = cxmad(z3, w54, x3); z3 = cxmad(z3, w52, x4);
    float2 z4 = x0; z4 = cxmad(z4, w54, x1); z4 = cxmad(z4, w53, x2); z4 = cxmad(z4, w52, x3); z4 = cxmad(z4, w51, x4);
    b1[5 * t] = z0; b1[5 * t + 1] = z1; b1[5 * t + 2] = z2; b1[5 * t + 3] = z3; b1[5 * t + 4] = z4;
  }
  __syncthreads();
  radix2_stage<5>  (b1, b0, lane);
  radix2_stage<10> (b0, b1, lane);
  radix2_stage<20> (b1, b0, lane);
  radix2_stage<40> (b0, b1, lane);
  radix2_stage<80> (b1, b0, lane);
  radix2_stage<160>(b0, b1, lane);
  radix2_stage<320>(b1, b0, lane);
}

// ---- stage A: row FFTs, transposed output. grid = chunk*16*80 blocks ----
__global__ __launch_bounds__(256) void stageA_kernel(const float* __restrict__ img,
                                                     float* __restrict__ AT, int p0) {
  __shared__ float2 lds[4][2][LSTR];
  int wv = threadIdx.x >> 6, lane = threadIdx.x & 63;
  int bx = blockIdx.x;
  int pp = bx / (NIMG * 80);
  int rem = bx - pp * (NIMG * 80);
  int i = rem / 80, hg = rem - i * 80;
  int h0 = hg * 4;
  int h = h0 + wv;
  int p = p0 + pp;
  const float2* src = (const float2*)img + ((size_t)(p * NIMG + i) * NH + h) * NH;
  float2* b0 = lds[wv][0];
  float2* b1 = lds[wv][1];
  float ah = apodf(h) * (1.0f / 640.0f);  // fold 1/sqrt(Kh*Kw) ortho norm
#pragma unroll
  for (int s = 0; s < 5; s++) {
    int w = lane + 64 * s;
    float2 v = src[w];
    float sc = apodf(w) * ah;
    b0[w] = make_float2(v.x * sc, v.y * sc);
    b0[w + 320] = make_float2(0.f, 0.f);
  }
  fft640(b0, b1, lane);
  // cooperative transposed write: AT[i][kw][h0+c] <- lds[c][0][kw]
  // lanes: c = tid&3 (which row), kw = tid>>2 (+64/pass): 4 lanes -> 32B contiguous
  int c = threadIdx.x & 3;
  int kwb = threadIdx.x >> 2;
  float2* dst = (float2*)AT + (size_t)(pp * NIMG + i) * NK * NH + h0 + c;
#pragma unroll
  for (int s = 0; s < 10; s++) {
    int kw = kwb + 64 * s;
    dst[(size_t)kw * NH] = lds[c][0][kw];
  }
}

// ---- stage B: column FFTs, fully coalesced. grid = chunk*16*160 blocks ----
__global__ __launch_bounds__(256) void stageB_kernel(const float* __restrict__ AT,
                                                     float* __restrict__ G) {
  __shared__ float2 lds[4][2][LSTR];
  int wv = threadIdx.x >> 6, lane = threadIdx.x & 63;
  int bx = blockIdx.x;
  int pi = bx / 160;                 // pp*NIMG + i
  int kwg = bx - pi * 160;
  int kw = kwg * 4 + wv;
  const float2* row = (const float2*)AT + ((size_t)pi * NK + kw) * NH;  // contiguous!
  float2* b0 = lds[wv][0];
  float2* b1 = lds[wv][1];
#pragma unroll
  for (int s = 0; s < 5; s++) {
    int h = lane + 64 * s;
    b0[h] = row[h];
    b0[h + 320] = make_float2(0.f, 0.f);
  }
  fft640(b0, b1, lane);
  float2* dst = (float2*)G + ((size_t)pi * NK + kw) * NK;  // transposed: kh contiguous
#pragma unroll
  for (int s = 0; s < 10; s++) {
    int kh = lane + 64 * s;
    dst[kh] = b0[kh];
  }
}

// ---- taps: per (phase, point): 6 weights+indices per dim + recentering phase ----
__global__ __launch_bounds__(256) void taps_kernel(const float* __restrict__ traj,
                                                   float* __restrict__ tapw,
                                                   int* __restrict__ tapi) {
  int t = blockIdx.x * 256 + threadIdx.x;
  if (t >= NPH * KLEN) return;
  int p = t / KLEN, l = t - p * KLEN;
  float inv_i0a = 1.0f / i0f(KB_ALPHA);
  float* wout = tapw + (size_t)t * 14;
  int* iout = tapi + (size_t)t * 12;
  float ang = 0.0f;
#pragma unroll
  for (int d = 0; d < 2; d++) {
    float om = traj[((size_t)p * 2 + d) * KLEN + l];
    float tt = om * 640.0f / 6.28318530717958647692f;
    float base = floorf(tt - 3.0f);
    ang += om * 160.0f;              // n_shift = 320//2
#pragma unroll
    for (int j = 0; j < 6; j++) {
      float kf = base + (float)(j + 1);
      float u = tt - kf;
      float arg = fmaxf(1.0f - (u * u) * (1.0f / 9.0f), 0.0f);
      wout[d * 6 + j] = i0f(KB_ALPHA * sqrtf(arg)) * inv_i0a;
      int ki = (int)kf + 640;        // kf in [-323,636] -> ki in [317,1276]
      if (ki >= 640) ki -= 640;
      iout[d * 6 + j] = ki;
    }
  }
  float s, c;
  sincosf(ang, &s, &c);              // accurate path: |ang| up to ~1005 rad
  wout[12] = c;
  wout[13] = s;
}

// ---- interp: XCD-pinned gather. grid = chunk*2000 blocks x 128 threads.
// xcd = bx&7 owns image xcd (blocks j<125) then image 8+xcd (j>=125); each
// image's 3.27MB grid stays resident in that XCD's 4MB L2. ----
__global__ __launch_bounds__(128) void interp_kernel(const float* __restrict__ G,
                                                     const float* __restrict__ tapw,
                                                     const int* __restrict__ tapi,
                                                     float* __restrict__ out, int p0) {
  int pp = blockIdx.x / 2000;
  int rem = blockIdx.x - pp * 2000;
  int x = rem & 7;                   // XCD (heuristic: round-robin dispatch)
  int j = rem >> 3;                  // 0..249
  int i = x + 8 * (j >= 125);
  int jj = (j >= 125) ? j - 125 : j;
  int l = jj * 128 + threadIdx.x;
  int p = p0 + pp;
  const float* w = tapw + (size_t)(p * KLEN + l) * 14;
  const int* ix = tapi + (size_t)(p * KLEN + l) * 12;
  const float2* g = (const float2*)G + (size_t)(pp * NIMG + i) * NK * NK;
  float whv[6]; int ihv[6];
#pragma unroll
  for (int jh = 0; jh < 6; jh++) { whv[jh] = w[jh]; ihv[jh] = ix[jh]; }
  float ar = 0.f, ai = 0.f;
#pragma unroll
  for (int jw = 0; jw < 6; jw++) {
    const float2* col = g + (size_t)ix[6 + jw] * NK;
    float sr = 0.f, si = 0.f;
#pragma unroll
    for (int jh = 0; jh < 6; jh++) {
      float2 v = col[ihv[jh]];
      sr = fmaf(whv[jh], v.x, sr);
      si = fmaf(whv[jh], v.y, si);
    }
    float wwj = w[6 + jw];
    ar = fmaf(wwj, sr, ar);
    ai = fmaf(wwj, si, ai);
  }
  float c = w[12], s = w[13];
  size_t o = ((size_t)(p * NIMG + i) * KLEN + l) * 2;
  out[o]     = ar * c - ai * s;
  out[o + 1] = ar * s + ai * c;
}

extern "C" void kernel_launch(void* const* d_in, const int* in_sizes, int n_in,
                              void* d_out, int out_size, void* d_ws, size_t ws_size,
                              hipStream_t stream) {
  const float* img  = (const float*)d_in[0];   // (1,5,8,2,320,320,2) f32
  const float* traj = (const float*)d_in[1];   // (5,2,16000) f32
  float* out = (float*)d_out;                  // (1,5,8,2,16000,2) f32

  char* ws = (char*)d_ws;
  float* tapw = (float*)ws;                               // 5*16000*14*4 = 4,480,000 B
  int*   tapi = (int*)(ws + 4480000);                     // 5*16000*12*4 = 3,840,000 B
  char*  heap = ws + 8320000;
  const size_t Ab = (size_t)NIMG * NH * NK * 2 * 4;       // 26,214,400 B / phase
  const size_t Gb = (size_t)NIMG * NK * NK * 2 * 4;       // 52,428,800 B / phase
  // all-phases layout if workspace allows (fewer launches), else per-phase loop
  int chunk = (ws_size >= (size_t)8320000 + 5 * (Ab + Gb)) ? 5 : 1;
  float* AT = (float*)heap;
  float* G = (float*)(heap + (size_t)chunk * Ab);

  taps_kernel<<<(NPH * KLEN + 255) / 256, 256, 0, stream>>>(traj, tapw, tapi);
  for (int p0 = 0; p0 < NPH; p0 += chunk) {
    stageA_kernel<<<chunk * NIMG * 80, 256, 0, stream>>>(img, AT, p0);
    stageB_kernel<<<chunk * NIMG * 160, 256, 0, stream>>>(AT, G);
    interp_kernel<<<chunk * 2000, 128, 0, stream>>>(G, tapw, tapi, out, p0);
  }
}

// Round 3
// 541.771 us; speedup vs baseline: 1.6868x; 1.3790x over previous
//
#include <hip/hip_runtime.h>
#include <cstdint>
#include <cstddef>

// NUFFT type-2, torchkbnufft-compatible (J=6, alpha=14.04, os=2).
// Pipeline per phase p (5 phases, 16 coil-images each, 320x320 -> 640x640):
//   stageA: apodize+pad rows, reg-FFT-640 along W -> A_T[i][kw][h] (LDS transpose, 1 barrier)
//   stageB: reg-FFT-640 along H (pad 320->640)    -> G[i][kw][kh]  (no LDS, no barriers)
//   interp: 6x6 KB taps gather + phase, XCD-pinned (image 3.27MB -> one XCD's 4MB L2)
// FFT-640 = four-step 10x64 in REGISTERS: per-lane zero-padded FFT-10 (2x FFT-5),
// twiddle, then 6 __shfl_xor butterfly stages (cross-lane FFT-64, DIF, bitrev out).
// Lane ends holding 10 consecutive kh -> contiguous float4 stores.

#define PI_F     3.14159265358979323846f
#define KB_ALPHA 14.04f
#define NPH  5
#define NIMG 16
#define NH   320
#define NK   640
#define KLEN 16000

// ---- modified Bessel I0 (A&S 9.8.1 / 9.8.2, rel err ~2e-7). I0(alpha) cancels
// between apodization (numerator) and tap weights (denominator). ----
__device__ __forceinline__ float i0f(float x) {
  if (x < 3.75f) {
    float t = x * (1.0f / 3.75f), t2 = t * t;
    return 1.0f + t2 * (3.5156229f + t2 * (3.0899424f + t2 * (1.2067492f +
                 t2 * (0.2659732f + t2 * (0.0360768f + t2 * 0.0045813f)))));
  }
  float t = 3.75f / x;
  float poly = 0.39894228f + t * (0.01328592f + t * (0.00225319f + t * (-0.00157565f +
               t * (0.00916281f + t * (-0.02057706f + t * (0.02635537f +
               t * (-0.01647633f + t * 0.00392377f)))))));
  return expf(x) * rsqrtf(x) * poly;
}

// apodization scale (1/FT(KB)); z^2 = alpha^2-(pi*J*u)^2 > 0 always for |u|<=0.25
__device__ __forceinline__ float apodf(int n) {
  float u = (float)(n - 160) * (1.0f / 640.0f);
  float pj = PI_F * 6.0f * u;
  float z = sqrtf(KB_ALPHA * KB_ALPHA - pj * pj);
  float sh = 0.5f * (expf(z) - expf(-z));     // sinh(z)
  return z * i0f(KB_ALPHA) / (6.0f * sh);     // 1/ft = z*I0a/(J*sinh z)
}

__device__ __forceinline__ float2 cadd(float2 a, float2 b) { return make_float2(a.x + b.x, a.y + b.y); }
__device__ __forceinline__ float2 csub(float2 a, float2 b) { return make_float2(a.x - b.x, a.y - b.y); }
__device__ __forceinline__ float2 cmul(float2 a, float2 b) {
  return make_float2(fmaf(a.x, b.x, -a.y * b.y), fmaf(a.x, b.y, a.y * b.x));
}
__device__ __forceinline__ float2 cxmad(float2 a, float2 w, float2 x) {
  a.x = fmaf(w.x, x.x, fmaf(-w.y, x.y, a.x));
  a.y = fmaf(w.x, x.y, fmaf( w.y, x.x, a.y));
  return a;
}

// direct 5-point DFT, forward (W5 = e^{-2pi i/5})
__device__ __forceinline__ void fft5(const float2 b[5], float2 z[5]) {
  const float2 w1 = make_float2( 0.309016994374947424f, -0.951056516295153572f);
  const float2 w2 = make_float2(-0.809016994374947424f, -0.587785252292473129f);
  const float2 w3 = make_float2(-0.809016994374947424f,  0.587785252292473129f);
  const float2 w4 = make_float2( 0.309016994374947424f,  0.951056516295153572f);
  z[0] = cadd(cadd(b[0], b[1]), cadd(cadd(b[2], b[3]), b[4]));
  z[1] = b[0]; z[1] = cxmad(z[1], w1, b[1]); z[1] = cxmad(z[1], w2, b[2]); z[1] = cxmad(z[1], w3, b[3]); z[1] = cxmad(z[1], w4, b[4]);
  z[2] = b[0]; z[2] = cxmad(z[2], w2, b[1]); z[2] = cxmad(z[2], w4, b[2]); z[2] = cxmad(z[2], w1, b[3]); z[2] = cxmad(z[2], w3, b[4]);
  z[3] = b[0]; z[3] = cxmad(z[3], w3, b[1]); z[3] = cxmad(z[3], w1, b[2]); z[3] = cxmad(z[3], w4, b[3]); z[3] = cxmad(z[3], w2, b[4]);
  z[4] = b[0]; z[4] = cxmad(z[4], w4, b[1]); z[4] = cxmad(z[4], w3, b[2]); z[4] = cxmad(z[4], w2, b[3]); z[4] = cxmad(z[4], w1, b[4]);
}

// Register FFT-640 of the zero-padded sequence x[64*n1 + lane] = b[n1] (n1=0..4;
// n1=5..9 implicitly zero). Returns k2 = bitrev6(lane); v[k1] = X[k1 + 10*k2].
__device__ __forceinline__ int fft640_reg(const float2 b[5], float2 v[10], int lane) {
  // FFT-10 with upper half zero: even outputs FFT5(b), odd outputs FFT5(b .* W10^n)
  const float2 t1 = make_float2( 0.809016994374947424f, -0.587785252292473129f); // W10^1
  const float2 t2 = make_float2( 0.309016994374947424f, -0.951056516295153572f); // W10^2
  const float2 t3 = make_float2(-0.309016994374947424f, -0.951056516295153572f); // W10^3
  const float2 t4 = make_float2(-0.809016994374947424f, -0.587785252292473129f); // W10^4
  float2 e[5], o[5], bp[5];
  fft5(b, e);
  bp[0] = b[0]; bp[1] = cmul(b[1], t1); bp[2] = cmul(b[2], t2);
  bp[3] = cmul(b[3], t3); bp[4] = cmul(b[4], t4);
  fft5(bp, o);
  v[0] = e[0]; v[2] = e[1]; v[4] = e[2]; v[6] = e[3]; v[8] = e[4];
  v[1] = o[0]; v[3] = o[1]; v[5] = o[2]; v[7] = o[3]; v[9] = o[4];
  // twiddle: v[k1] *= W640^{lane*k1}
  float sn, cs;
  __sincosf(-2.0f * PI_F * (float)lane * (1.0f / 640.0f), &sn, &cs);
  float2 w1 = make_float2(cs, sn), wk = w1;
  v[1] = cmul(v[1], wk);
#pragma unroll
  for (int k = 2; k < 10; k++) { wk = cmul(wk, w1); v[k] = cmul(v[k], wk); }
  // cross-lane FFT-64 over n2=lane: DIF radix-2, 6 shuffle stages, bitrev output
#pragma unroll
  for (int s = 5; s >= 0; s--) {
    int half = 1 << s;
    int up = lane & half;
    float ang = -(PI_F / (float)half) * (float)(lane & (half - 1));
    float ss, cc;
    __sincosf(ang, &ss, &cc);
    float2 tw = make_float2(cc, ss);
#pragma unroll
    for (int q = 0; q < 10; q++) {
      float2 oth;
      oth.x = __shfl_xor(v[q].x, half, 64);
      oth.y = __shfl_xor(v[q].y, half, 64);
      float2 sum = cadd(v[q], oth);
      float2 dif = cmul(csub(oth, v[q]), tw);
      v[q] = up ? dif : sum;
    }
  }
  return __brev(lane) >> 26;
}

// ---- stage A: row FFTs, transposed output via single-buffer LDS (1 barrier).
// grid = chunk*16*80 blocks x 256 (4 waves = 4 consecutive rows h) ----
__global__ __launch_bounds__(256) void stageA_kernel(const float* __restrict__ img,
                                                     float* __restrict__ AT, int p0) {
  __shared__ float2 lds[4 * 705];   // per-row stride 705 float2 (odd: breaks quad conflicts)
  int wv = threadIdx.x >> 6, lane = threadIdx.x & 63;
  int bx = blockIdx.x;
  int pp = bx / (NIMG * 80);
  int rem = bx - pp * (NIMG * 80);
  int i = rem / 80, hg = rem - i * 80;
  int h0 = hg * 4, h = h0 + wv;
  int p = p0 + pp;
  const float2* src = (const float2*)img + ((size_t)(p * NIMG + i) * NH + h) * NH;
  float ah = apodf(h) * (1.0f / 640.0f);  // fold 1/sqrt(Kh*Kw) ortho norm
  float2 b[5];
#pragma unroll
  for (int j = 0; j < 5; j++) {
    float2 x = src[lane + 64 * j];
    float sc = apodf(lane + 64 * j) * ah;
    b[j] = make_float2(x.x * sc, x.y * sc);
  }
  float2 v[10];
  int k2 = fft640_reg(b, v, lane);
  float2* rowl = lds + wv * 705 + 11 * k2;   // kw=k1+10*k2 stored at 11*k2+k1
#pragma unroll
  for (int k = 0; k < 10; k++) rowl[k] = v[k];
  __syncthreads();
  // cooperative transposed write: AT[kw][h0+c], quad of lanes = 32B contiguous
  int c = threadIdx.x & 3, kwb = threadIdx.x >> 2;
  float2* dst = (float2*)AT + (size_t)(pp * NIMG + i) * NK * NH + h0 + c;
#pragma unroll
  for (int s = 0; s < 10; s++) {
    int kw = kwb + 64 * s;
    int q2 = (kw * 6554) >> 16;     // kw/10 (exact for kw<1638)
    int q1 = kw - 10 * q2;
    dst[(size_t)kw * NH] = lds[c * 705 + 11 * q2 + q1];
  }
}

// ---- stage B: column FFTs, pure-register, no LDS, no barriers.
// grid = chunk*16*160 blocks x 256 (4 independent waves = 4 kw columns) ----
__global__ __launch_bounds__(256) void stageB_kernel(const float* __restrict__ AT,
                                                     float* __restrict__ G) {
  int wv = threadIdx.x >> 6, lane = threadIdx.x & 63;
  int bx = blockIdx.x;
  int pi = bx / 160;                 // pp*NIMG + i
  int kwg = bx - pi * 160;
  int kw = kwg * 4 + wv;
  const float2* rowp = (const float2*)AT + ((size_t)pi * NK + kw) * NH;  // contiguous
  float2 b[5];
#pragma unroll
  for (int j = 0; j < 5; j++) b[j] = rowp[lane + 64 * j];
  float2 v[10];
  int k2 = fft640_reg(b, v, lane);
  // lane writes 10 consecutive kh = [10*k2, 10*k2+10) as 5 float4 stores
  float4* dst = (float4*)((float2*)G + ((size_t)pi * NK + kw) * NK + 10 * k2);
#pragma unroll
  for (int m = 0; m < 5; m++)
    dst[m] = make_float4(v[2 * m].x, v[2 * m].y, v[2 * m + 1].x, v[2 * m + 1].y);
}

// ---- taps: per (phase, point): 6 weights+indices per dim + recentering phase ----
__global__ __launch_bounds__(256) void taps_kernel(const float* __restrict__ traj,
                                                   float* __restrict__ tapw,
                                                   int* __restrict__ tapi) {
  int t = blockIdx.x * 256 + threadIdx.x;
  if (t >= NPH * KLEN) return;
  int p = t / KLEN, l = t - p * KLEN;
  float inv_i0a = 1.0f / i0f(KB_ALPHA);
  float* wout = tapw + (size_t)t * 14;
  int* iout = tapi + (size_t)t * 12;
  float ang = 0.0f;
#pragma unroll
  for (int d = 0; d < 2; d++) {
    float om = traj[((size_t)p * 2 + d) * KLEN + l];
    float tt = om * 640.0f / 6.28318530717958647692f;
    float base = floorf(tt - 3.0f);
    ang += om * 160.0f;              // n_shift = 320//2
#pragma unroll
    for (int j = 0; j < 6; j++) {
      float kf = base + (float)(j + 1);
      float u = tt - kf;
      float arg = fmaxf(1.0f - (u * u) * (1.0f / 9.0f), 0.0f);
      wout[d * 6 + j] = i0f(KB_ALPHA * sqrtf(arg)) * inv_i0a;
      int ki = (int)kf + 640;        // kf in [-323,636] -> ki in [317,1276]
      if (ki >= 640) ki -= 640;
      iout[d * 6 + j] = ki;
    }
  }
  float s, c;
  sincosf(ang, &s, &c);              // accurate path: |ang| up to ~1005 rad
  wout[12] = c;
  wout[13] = s;
}

// ---- interp: XCD-pinned gather. grid = chunk*2000 blocks x 128 threads.
// xcd = bx&7 owns image xcd (blocks j<125) then image 8+xcd (j>=125); each
// image's 3.27MB grid stays resident in that XCD's 4MB L2. ----
__global__ __launch_bounds__(128) void interp_kernel(const float* __restrict__ G,
                                                     const float* __restrict__ tapw,
                                                     const int* __restrict__ tapi,
                                                     float* __restrict__ out, int p0) {
  int pp = blockIdx.x / 2000;
  int rem = blockIdx.x - pp * 2000;
  int x = rem & 7;                   // XCD (heuristic: round-robin dispatch)
  int j = rem >> 3;                  // 0..249
  int i = x + 8 * (j >= 125);
  int jj = (j >= 125) ? j - 125 : j;
  int l = jj * 128 + threadIdx.x;
  int p = p0 + pp;
  const float* w = tapw + (size_t)(p * KLEN + l) * 14;
  const int* ix = tapi + (size_t)(p * KLEN + l) * 12;
  const float2* g = (const float2*)G + (size_t)(pp * NIMG + i) * NK * NK;
  float whv[6]; int ihv[6];
#pragma unroll
  for (int jh = 0; jh < 6; jh++) { whv[jh] = w[jh]; ihv[jh] = ix[jh]; }
  float ar = 0.f, ai = 0.f;
#pragma unroll
  for (int jw = 0; jw < 6; jw++) {
    const float2* col = g + (size_t)ix[6 + jw] * NK;
    float sr = 0.f, si = 0.f;
#pragma unroll
    for (int jh = 0; jh < 6; jh++) {
      float2 v = col[ihv[jh]];
      sr = fmaf(whv[jh], v.x, sr);
      si = fmaf(whv[jh], v.y, si);
    }
    float wwj = w[6 + jw];
    ar = fmaf(wwj, sr, ar);
    ai = fmaf(wwj, si, ai);
  }
  float c = w[12], s = w[13];
  size_t o = ((size_t)(p * NIMG + i) * KLEN + l) * 2;
  out[o]     = ar * c - ai * s;
  out[o + 1] = ar * s + ai * c;
}

extern "C" void kernel_launch(void* const* d_in, const int* in_sizes, int n_in,
                              void* d_out, int out_size, void* d_ws, size_t ws_size,
                              hipStream_t stream) {
  const float* img  = (const float*)d_in[0];   // (1,5,8,2,320,320,2) f32
  const float* traj = (const float*)d_in[1];   // (5,2,16000) f32
  float* out = (float*)d_out;                  // (1,5,8,2,16000,2) f32

  char* ws = (char*)d_ws;
  float* tapw = (float*)ws;                               // 5*16000*14*4 = 4,480,000 B
  int*   tapi = (int*)(ws + 4480000);                     // 5*16000*12*4 = 3,840,000 B
  char*  heap = ws + 8320000;
  const size_t Ab = (size_t)NIMG * NH * NK * 2 * 4;       // 26,214,400 B / phase
  const size_t Gb = (size_t)NIMG * NK * NK * 2 * 4;       // 52,428,800 B / phase
  // all-phases layout if workspace allows (fewer launches), else per-phase loop
  int chunk = (ws_size >= (size_t)8320000 + 5 * (Ab + Gb)) ? 5 : 1;
  float* AT = (float*)heap;
  float* G = (float*)(heap + (size_t)chunk * Ab);

  taps_kernel<<<(NPH * KLEN + 255) / 256, 256, 0, stream>>>(traj, tapw, tapi);
  for (int p0 = 0; p0 < NPH; p0 += chunk) {
    stageA_kernel<<<chunk * NIMG * 80, 256, 0, stream>>>(img, AT, p0);
    stageB_kernel<<<chunk * NIMG * 160, 256, 0, stream>>>(AT, G);
    interp_kernel<<<chunk * 2000, 128, 0, stream>>>(G, tapw, tapi, out, p0);
  }
}

// Round 4
// 485.578 us; speedup vs baseline: 1.8820x; 1.1157x over previous
//
#include <hip/hip_runtime.h>
#include <cstdint>
#include <cstddef>

// NUFFT type-2, torchkbnufft-compatible (J=6, alpha=14.04, os=2).
// Pipeline per phase p (5 phases, 16 coil-images each, 320x320 -> 640x640):
//   stageA: apodize+pad rows, reg-FFT-640 along W -> A_T[i][kw][h] (LDS transpose, 1 barrier)
//   stageB: reg-FFT-640 along H (pad 320->640)    -> G[i][kw][kh]  (no LDS, no barriers)
//   interp: 6x6 KB taps gather + phase, XCD-pinned (image 3.27MB -> one XCD's 4MB L2),
//           all-36-gathers-in-flight for MLP (latency-bound otherwise)
// FFT-640 = four-step 10x64 in REGISTERS: per-lane zero-padded FFT-10 (2x FFT-5),
// twiddle, then 6 __shfl_xor butterfly stages (cross-lane FFT-64, DIF, bitrev out).

#define PI_F     3.14159265358979323846f
#define KB_ALPHA 14.04f
#define NPH  5
#define NIMG 16
#define NH   320
#define NK   640
#define KLEN 16000

// ---- modified Bessel I0 (A&S 9.8.1 / 9.8.2, rel err ~2e-7). I0(alpha) cancels
// between apodization (numerator) and tap weights (denominator). ----
__device__ __forceinline__ float i0f(float x) {
  if (x < 3.75f) {
    float t = x * (1.0f / 3.75f), t2 = t * t;
    return 1.0f + t2 * (3.5156229f + t2 * (3.0899424f + t2 * (1.2067492f +
                 t2 * (0.2659732f + t2 * (0.0360768f + t2 * 0.0045813f)))));
  }
  float t = 3.75f / x;
  float poly = 0.39894228f + t * (0.01328592f + t * (0.00225319f + t * (-0.00157565f +
               t * (0.00916281f + t * (-0.02057706f + t * (0.02635537f +
               t * (-0.01647633f + t * 0.00392377f)))))));
  return expf(x) * rsqrtf(x) * poly;
}

// apodization scale (1/FT(KB)); z^2 = alpha^2-(pi*J*u)^2 > 0 always for |u|<=0.25
__device__ __forceinline__ float apodf(int n) {
  float u = (float)(n - 160) * (1.0f / 640.0f);
  float pj = PI_F * 6.0f * u;
  float z = sqrtf(KB_ALPHA * KB_ALPHA - pj * pj);
  float sh = 0.5f * (expf(z) - expf(-z));     // sinh(z)
  return z * i0f(KB_ALPHA) / (6.0f * sh);     // 1/ft = z*I0a/(J*sinh z)
}

__device__ __forceinline__ float2 cadd(float2 a, float2 b) { return make_float2(a.x + b.x, a.y + b.y); }
__device__ __forceinline__ float2 csub(float2 a, float2 b) { return make_float2(a.x - b.x, a.y - b.y); }
__device__ __forceinline__ float2 cmul(float2 a, float2 b) {
  return make_float2(fmaf(a.x, b.x, -a.y * b.y), fmaf(a.x, b.y, a.y * b.x));
}
__device__ __forceinline__ float2 cxmad(float2 a, float2 w, float2 x) {
  a.x = fmaf(w.x, x.x, fmaf(-w.y, x.y, a.x));
  a.y = fmaf(w.x, x.y, fmaf( w.y, x.x, a.y));
  return a;
}

// direct 5-point DFT, forward (W5 = e^{-2pi i/5})
__device__ __forceinline__ void fft5(const float2 b[5], float2 z[5]) {
  const float2 w1 = make_float2( 0.309016994374947424f, -0.951056516295153572f);
  const float2 w2 = make_float2(-0.809016994374947424f, -0.587785252292473129f);
  const float2 w3 = make_float2(-0.809016994374947424f,  0.587785252292473129f);
  const float2 w4 = make_float2( 0.309016994374947424f,  0.951056516295153572f);
  z[0] = cadd(cadd(b[0], b[1]), cadd(cadd(b[2], b[3]), b[4]));
  z[1] = b[0]; z[1] = cxmad(z[1], w1, b[1]); z[1] = cxmad(z[1], w2, b[2]); z[1] = cxmad(z[1], w3, b[3]); z[1] = cxmad(z[1], w4, b[4]);
  z[2] = b[0]; z[2] = cxmad(z[2], w2, b[1]); z[2] = cxmad(z[2], w4, b[2]); z[2] = cxmad(z[2], w1, b[3]); z[2] = cxmad(z[2], w3, b[4]);
  z[3] = b[0]; z[3] = cxmad(z[3], w3, b[1]); z[3] = cxmad(z[3], w1, b[2]); z[3] = cxmad(z[3], w4, b[3]); z[3] = cxmad(z[3], w2, b[4]);
  z[4] = b[0]; z[4] = cxmad(z[4], w4, b[1]); z[4] = cxmad(z[4], w3, b[2]); z[4] = cxmad(z[4], w2, b[3]); z[4] = cxmad(z[4], w1, b[4]);
}

// Register FFT-640 of the zero-padded sequence x[64*n1 + lane] = b[n1] (n1=0..4;
// n1=5..9 implicitly zero). Returns k2 = bitrev6(lane); v[k1] = X[k1 + 10*k2].
__device__ __forceinline__ int fft640_reg(const float2 b[5], float2 v[10], int lane) {
  // FFT-10 with upper half zero: even outputs FFT5(b), odd outputs FFT5(b .* W10^n)
  const float2 t1 = make_float2( 0.809016994374947424f, -0.587785252292473129f); // W10^1
  const float2 t2 = make_float2( 0.309016994374947424f, -0.951056516295153572f); // W10^2
  const float2 t3 = make_float2(-0.309016994374947424f, -0.951056516295153572f); // W10^3
  const float2 t4 = make_float2(-0.809016994374947424f, -0.587785252292473129f); // W10^4
  float2 e[5], o[5], bp[5];
  fft5(b, e);
  bp[0] = b[0]; bp[1] = cmul(b[1], t1); bp[2] = cmul(b[2], t2);
  bp[3] = cmul(b[3], t3); bp[4] = cmul(b[4], t4);
  fft5(bp, o);
  v[0] = e[0]; v[2] = e[1]; v[4] = e[2]; v[6] = e[3]; v[8] = e[4];
  v[1] = o[0]; v[3] = o[1]; v[5] = o[2]; v[7] = o[3]; v[9] = o[4];
  // twiddle: v[k1] *= W640^{lane*k1}
  float sn, cs;
  __sincosf(-2.0f * PI_F * (float)lane * (1.0f / 640.0f), &sn, &cs);
  float2 w1 = make_float2(cs, sn), wk = w1;
  v[1] = cmul(v[1], wk);
#pragma unroll
  for (int k = 2; k < 10; k++) { wk = cmul(wk, w1); v[k] = cmul(v[k], wk); }
  // cross-lane FFT-64 over n2=lane: DIF radix-2, 6 shuffle stages, bitrev output
#pragma unroll
  for (int s = 5; s >= 0; s--) {
    int half = 1 << s;
    int up = lane & half;
    float ang = -(PI_F / (float)half) * (float)(lane & (half - 1));
    float ss, cc;
    __sincosf(ang, &ss, &cc);
    float2 tw = make_float2(cc, ss);
#pragma unroll
    for (int q = 0; q < 10; q++) {
      float2 oth;
      oth.x = __shfl_xor(v[q].x, half, 64);
      oth.y = __shfl_xor(v[q].y, half, 64);
      float2 sum = cadd(v[q], oth);
      float2 dif = cmul(csub(oth, v[q]), tw);
      v[q] = up ? dif : sum;
    }
  }
  return __brev(lane) >> 26;
}

// ---- stage A: row FFTs, transposed output via single-buffer LDS (1 barrier).
// grid = chunk*16*80 blocks x 256 (4 waves = 4 consecutive rows h) ----
__global__ __launch_bounds__(256) void stageA_kernel(const float* __restrict__ img,
                                                     float* __restrict__ AT, int p0) {
  __shared__ float2 lds[4 * 705];   // per-row stride 705 float2 (odd: breaks quad conflicts)
  int wv = threadIdx.x >> 6, lane = threadIdx.x & 63;
  int bx = blockIdx.x;
  int pp = bx / (NIMG * 80);
  int rem = bx - pp * (NIMG * 80);
  int i = rem / 80, hg = rem - i * 80;
  int h0 = hg * 4, h = h0 + wv;
  int p = p0 + pp;
  const float2* src = (const float2*)img + ((size_t)(p * NIMG + i) * NH + h) * NH;
  float ah = apodf(h) * (1.0f / 640.0f);  // fold 1/sqrt(Kh*Kw) ortho norm
  float2 b[5];
#pragma unroll
  for (int j = 0; j < 5; j++) {
    float2 x = src[lane + 64 * j];
    float sc = apodf(lane + 64 * j) * ah;
    b[j] = make_float2(x.x * sc, x.y * sc);
  }
  float2 v[10];
  int k2 = fft640_reg(b, v, lane);
  float2* rowl = lds + wv * 705 + 11 * k2;   // kw=k1+10*k2 stored at 11*k2+k1
#pragma unroll
  for (int k = 0; k < 10; k++) rowl[k] = v[k];
  __syncthreads();
  // cooperative transposed write: AT[kw][h0+c], quad of lanes = 32B contiguous
  int c = threadIdx.x & 3, kwb = threadIdx.x >> 2;
  float2* dst = (float2*)AT + (size_t)(pp * NIMG + i) * NK * NH + h0 + c;
#pragma unroll
  for (int s = 0; s < 10; s++) {
    int kw = kwb + 64 * s;
    int q2 = (kw * 6554) >> 16;     // kw/10 (exact for kw<1638)
    int q1 = kw - 10 * q2;
    dst[(size_t)kw * NH] = lds[c * 705 + 11 * q2 + q1];
  }
}

// ---- stage B: column FFTs, pure-register, no LDS, no barriers.
// grid = chunk*16*160 blocks x 256 (4 independent waves = 4 kw columns) ----
__global__ __launch_bounds__(256) void stageB_kernel(const float* __restrict__ AT,
                                                     float* __restrict__ G) {
  int wv = threadIdx.x >> 6, lane = threadIdx.x & 63;
  int bx = blockIdx.x;
  int pi = bx / 160;                 // pp*NIMG + i
  int kwg = bx - pi * 160;
  int kw = kwg * 4 + wv;
  const float2* rowp = (const float2*)AT + ((size_t)pi * NK + kw) * NH;  // contiguous
  float2 b[5];
#pragma unroll
  for (int j = 0; j < 5; j++) b[j] = rowp[lane + 64 * j];
  float2 v[10];
  int k2 = fft640_reg(b, v, lane);
  // lane writes 10 consecutive kh = [10*k2, 10*k2+10) as 5 float4 stores
  float4* dst = (float4*)((float2*)G + ((size_t)pi * NK + kw) * NK + 10 * k2);
#pragma unroll
  for (int m = 0; m < 5; m++)
    dst[m] = make_float4(v[2 * m].x, v[2 * m].y, v[2 * m + 1].x, v[2 * m + 1].y);
}

// ---- taps: per (phase, point): 6 weights+indices per dim + recentering phase.
// tapw stride 16 floats (64B, float4-loadable); tapi stride 12 ints (48B, 16B-aligned) ----
__global__ __launch_bounds__(256) void taps_kernel(const float* __restrict__ traj,
                                                   float* __restrict__ tapw,
                                                   int* __restrict__ tapi) {
  int t = blockIdx.x * 256 + threadIdx.x;
  if (t >= NPH * KLEN) return;
  int p = t / KLEN, l = t - p * KLEN;
  float inv_i0a = 1.0f / i0f(KB_ALPHA);
  float* wout = tapw + (size_t)t * 16;
  int* iout = tapi + (size_t)t * 12;
  float ang = 0.0f;
#pragma unroll
  for (int d = 0; d < 2; d++) {
    float om = traj[((size_t)p * 2 + d) * KLEN + l];
    float tt = om * 640.0f / 6.28318530717958647692f;
    float base = floorf(tt - 3.0f);
    ang += om * 160.0f;              // n_shift = 320//2
#pragma unroll
    for (int j = 0; j < 6; j++) {
      float kf = base + (float)(j + 1);
      float u = tt - kf;
      float arg = fmaxf(1.0f - (u * u) * (1.0f / 9.0f), 0.0f);
      wout[d * 6 + j] = i0f(KB_ALPHA * sqrtf(arg)) * inv_i0a;
      int ki = (int)kf + 640;        // kf in [-323,636] -> ki in [317,1276]
      if (ki >= 640) ki -= 640;
      iout[d * 6 + j] = ki;
    }
  }
  float s, c;
  sincosf(ang, &s, &c);              // accurate path: |ang| up to ~1005 rad
  wout[12] = c;
  wout[13] = s;
  wout[14] = 0.f;
  wout[15] = 0.f;
}

// ---- interp: XCD-pinned gather, full-MLP. grid = 2000 blocks x 128 threads.
// xcd = bx&7 owns image xcd (blocks j<125) then image 8+xcd (j>=125); each
// image's 3.27MB grid stays resident in that XCD's 4MB L2. All 36 gathers are
// issued before any use (latency-bound otherwise: R3 showed VALUBusy 1.9%). ----
__global__ __launch_bounds__(128) void interp_kernel(const float* __restrict__ G,
                                                     const float* __restrict__ tapw,
                                                     const int* __restrict__ tapi,
                                                     float* __restrict__ out, int p) {
  int rem = blockIdx.x;
  int x = rem & 7;                   // XCD (heuristic: round-robin dispatch)
  int j = rem >> 3;                  // 0..249
  int i = x + 8 * (j >= 125);
  int jj = (j >= 125) ? j - 125 : j;
  int l = jj * 128 + threadIdx.x;
  // vectorized tap loads
  const float4* w4 = (const float4*)(tapw + (size_t)(p * KLEN + l) * 16);
  float4 wa = w4[0], wb = w4[1], wc = w4[2], wd = w4[3];
  const int4* i4 = (const int4*)(tapi + (size_t)(p * KLEN + l) * 12);
  int4 ia = i4[0], ib = i4[1], ic = i4[2];
  float whv[6] = {wa.x, wa.y, wa.z, wa.w, wb.x, wb.y};
  float wwv[6] = {wb.z, wb.w, wc.x, wc.y, wc.z, wc.w};
  int   ihv[6] = {ia.x, ia.y, ia.z, ia.w, ib.x, ib.y};
  int   iwv[6] = {ib.z, ib.w, ic.x, ic.y, ic.z, ic.w};
  const float2* g = (const float2*)G + (size_t)i * NK * NK;
  // all 36 offsets, then all 36 loads in flight, then reduce
  int offs[36];
#pragma unroll
  for (int jw = 0; jw < 6; jw++) {
    int cb = iwv[jw] * NK;
#pragma unroll
    for (int jh = 0; jh < 6; jh++) offs[jw * 6 + jh] = cb + ihv[jh];
  }
  float2 vals[36];
#pragma unroll
  for (int t = 0; t < 36; t++) vals[t] = g[offs[t]];
  float ar = 0.f, ai = 0.f;
#pragma unroll
  for (int jw = 0; jw < 6; jw++) {
    float sr = 0.f, si = 0.f;
#pragma unroll
    for (int jh = 0; jh < 6; jh++) {
      float2 v = vals[jw * 6 + jh];
      sr = fmaf(whv[jh], v.x, sr);
      si = fmaf(whv[jh], v.y, si);
    }
    ar = fmaf(wwv[jw], sr, ar);
    ai = fmaf(wwv[jw], si, ai);
  }
  float c = wd.x, s = wd.y;
  size_t o = (size_t)(p * NIMG + i) * KLEN + l;
  ((float2*)out)[o] = make_float2(ar * c - ai * s, ar * s + ai * c);
}

extern "C" void kernel_launch(void* const* d_in, const int* in_sizes, int n_in,
                              void* d_out, int out_size, void* d_ws, size_t ws_size,
                              hipStream_t stream) {
  const float* img  = (const float*)d_in[0];   // (1,5,8,2,320,320,2) f32
  const float* traj = (const float*)d_in[1];   // (5,2,16000) f32
  float* out = (float*)d_out;                  // (1,5,8,2,16000,2) f32

  char* ws = (char*)d_ws;
  float* tapw = (float*)ws;                               // 5*16000*16*4 = 5,120,000 B
  int*   tapi = (int*)(ws + 5120000);                     // 5*16000*12*4 = 3,840,000 B
  char*  heap = ws + 8960000;
  const size_t Ab = (size_t)NIMG * NH * NK * 2 * 4;       // 26,214,400 B / phase
  const size_t Gb = (size_t)NIMG * NK * NK * 2 * 4;       // 52,428,800 B / phase
  // all-phases layout if workspace allows (fewer launches), else per-phase loop
  int chunk = (ws_size >= (size_t)8960000 + 5 * (Ab + Gb)) ? 5 : 1;
  float* AT = (float*)heap;
  float* G = (float*)(heap + (size_t)chunk * Ab);

  taps_kernel<<<(NPH * KLEN + 255) / 256, 256, 0, stream>>>(traj, tapw, tapi);
  for (int p0 = 0; p0 < NPH; p0 += chunk) {
    stageA_kernel<<<chunk * NIMG * 80, 256, 0, stream>>>(img, AT, p0);
    stageB_kernel<<<chunk * NIMG * 160, 256, 0, stream>>>(AT, G);
    // interp stays per-phase: one phase's 16 images = 2 per XCD keeps L2 pinning
    for (int q = 0; q < chunk; q++) {
      float* Gq = (float*)((char*)G + (size_t)q * Gb);
      interp_kernel<<<2000, 128, 0, stream>>>(Gq, tapw, tapi, out, p0 + q);
    }
  }
}

// Round 5
// 446.612 us; speedup vs baseline: 2.0462x; 1.0872x over previous
//
#include <hip/hip_runtime.h>
#include <hip/hip_fp16.h>
#include <cstdint>
#include <cstddef>

// NUFFT type-2, torchkbnufft-compatible (J=6, alpha=14.04, os=2).
// Pipeline (5 phases, 16 coil-images each, 320x320 -> 640x640):
//   taps:   KB weights/indices/phase per (phase,point)
//   stageA: ALL phases, apodize+pad rows, reg-FFT-640 along W -> AT[pi][kw][h] fp16
//           (LDS transpose, nontemporal stores: AT is a stream, keep out of L2)
//   per phase p:
//     stageB: reg-FFT-640 along H -> G[i][kw][kh] fp16, XCD-PINNED per image
//             (image i on XCD i%8; its 1.64MB grid stays in that XCD's 4MB L2;
//              two images/XCD = 3.3MB, fits)
//     interp: 6x6 KB gather, XCD-pinned to the SAME XCD -> gathers hit hot L2.
//             sched_barrier(0) forces all 36 gathers in flight (R4: VGPR=24
//             proved the compiler was re-serializing them into 6-deep batches).
// FFT-640 = four-step 10x64 in registers: zero-padded FFT-10 (2x FFT-5), twiddle,
// 6 __shfl_xor butterfly stages. fp16 storage: G/AT rel err ~5e-4 -> output err
// ~1e-3, threshold 4.06e-2 (R4 absmax 0.0078).

#define PI_F     3.14159265358979323846f
#define KB_ALPHA 14.04f
#define NPH  5
#define NIMG 16
#define NH   320
#define NK   640
#define KLEN 16000

__device__ __forceinline__ uint32_t f2_to_h2(float2 v) {
  union { __half2 h; uint32_t u; } cv;
  cv.h = __float22half2_rn(v);
  return cv.u;
}
__device__ __forceinline__ float2 h2_to_f2(uint32_t u) {
  union { uint32_t u; __half2 h; } cv;
  cv.u = u;
  return __half22float2(cv.h);
}

// ---- modified Bessel I0 (A&S 9.8.1 / 9.8.2, rel err ~2e-7). I0(alpha) cancels
// between apodization (numerator) and tap weights (denominator). ----
__device__ __forceinline__ float i0f(float x) {
  if (x < 3.75f) {
    float t = x * (1.0f / 3.75f), t2 = t * t;
    return 1.0f + t2 * (3.5156229f + t2 * (3.0899424f + t2 * (1.2067492f +
                 t2 * (0.2659732f + t2 * (0.0360768f + t2 * 0.0045813f)))));
  }
  float t = 3.75f / x;
  float poly = 0.39894228f + t * (0.01328592f + t * (0.00225319f + t * (-0.00157565f +
               t * (0.00916281f + t * (-0.02057706f + t * (0.02635537f +
               t * (-0.01647633f + t * 0.00392377f)))))));
  return expf(x) * rsqrtf(x) * poly;
}

// apodization scale (1/FT(KB)); z^2 = alpha^2-(pi*J*u)^2 > 0 always for |u|<=0.25
__device__ __forceinline__ float apodf(int n) {
  float u = (float)(n - 160) * (1.0f / 640.0f);
  float pj = PI_F * 6.0f * u;
  float z = sqrtf(KB_ALPHA * KB_ALPHA - pj * pj);
  float sh = 0.5f * (expf(z) - expf(-z));     // sinh(z)
  return z * i0f(KB_ALPHA) / (6.0f * sh);     // 1/ft = z*I0a/(J*sinh z)
}

__device__ __forceinline__ float2 cadd(float2 a, float2 b) { return make_float2(a.x + b.x, a.y + b.y); }
__device__ __forceinline__ float2 csub(float2 a, float2 b) { return make_float2(a.x - b.x, a.y - b.y); }
__device__ __forceinline__ float2 cmul(float2 a, float2 b) {
  return make_float2(fmaf(a.x, b.x, -a.y * b.y), fmaf(a.x, b.y, a.y * b.x));
}
__device__ __forceinline__ float2 cxmad(float2 a, float2 w, float2 x) {
  a.x = fmaf(w.x, x.x, fmaf(-w.y, x.y, a.x));
  a.y = fmaf(w.x, x.y, fmaf( w.y, x.x, a.y));
  return a;
}

// direct 5-point DFT, forward (W5 = e^{-2pi i/5})
__device__ __forceinline__ void fft5(const float2 b[5], float2 z[5]) {
  const float2 w1 = make_float2( 0.309016994374947424f, -0.951056516295153572f);
  const float2 w2 = make_float2(-0.809016994374947424f, -0.587785252292473129f);
  const float2 w3 = make_float2(-0.809016994374947424f,  0.587785252292473129f);
  const float2 w4 = make_float2( 0.309016994374947424f,  0.951056516295153572f);
  z[0] = cadd(cadd(b[0], b[1]), cadd(cadd(b[2], b[3]), b[4]));
  z[1] = b[0]; z[1] = cxmad(z[1], w1, b[1]); z[1] = cxmad(z[1], w2, b[2]); z[1] = cxmad(z[1], w3, b[3]); z[1] = cxmad(z[1], w4, b[4]);
  z[2] = b[0]; z[2] = cxmad(z[2], w2, b[1]); z[2] = cxmad(z[2], w4, b[2]); z[2] = cxmad(z[2], w1, b[3]); z[2] = cxmad(z[2], w3, b[4]);
  z[3] = b[0]; z[3] = cxmad(z[3], w3, b[1]); z[3] = cxmad(z[3], w1, b[2]); z[3] = cxmad(z[3], w4, b[3]); z[3] = cxmad(z[3], w2, b[4]);
  z[4] = b[0]; z[4] = cxmad(z[4], w4, b[1]); z[4] = cxmad(z[4], w3, b[2]); z[4] = cxmad(z[4], w2, b[3]); z[4] = cxmad(z[4], w1, b[4]);
}

// Register FFT-640 of the zero-padded sequence x[64*n1 + lane] = b[n1] (n1=0..4;
// n1=5..9 implicitly zero). Returns k2 = bitrev6(lane); v[k1] = X[k1 + 10*k2].
__device__ __forceinline__ int fft640_reg(const float2 b[5], float2 v[10], int lane) {
  // FFT-10 with upper half zero: even outputs FFT5(b), odd outputs FFT5(b .* W10^n)
  const float2 t1 = make_float2( 0.809016994374947424f, -0.587785252292473129f); // W10^1
  const float2 t2 = make_float2( 0.309016994374947424f, -0.951056516295153572f); // W10^2
  const float2 t3 = make_float2(-0.309016994374947424f, -0.951056516295153572f); // W10^3
  const float2 t4 = make_float2(-0.809016994374947424f, -0.587785252292473129f); // W10^4
  float2 e[5], o[5], bp[5];
  fft5(b, e);
  bp[0] = b[0]; bp[1] = cmul(b[1], t1); bp[2] = cmul(b[2], t2);
  bp[3] = cmul(b[3], t3); bp[4] = cmul(b[4], t4);
  fft5(bp, o);
  v[0] = e[0]; v[2] = e[1]; v[4] = e[2]; v[6] = e[3]; v[8] = e[4];
  v[1] = o[0]; v[3] = o[1]; v[5] = o[2]; v[7] = o[3]; v[9] = o[4];
  // twiddle: v[k1] *= W640^{lane*k1}
  float sn, cs;
  __sincosf(-2.0f * PI_F * (float)lane * (1.0f / 640.0f), &sn, &cs);
  float2 w1 = make_float2(cs, sn), wk = w1;
  v[1] = cmul(v[1], wk);
#pragma unroll
  for (int k = 2; k < 10; k++) { wk = cmul(wk, w1); v[k] = cmul(v[k], wk); }
  // cross-lane FFT-64 over n2=lane: DIF radix-2, 6 shuffle stages, bitrev output
#pragma unroll
  for (int s = 5; s >= 0; s--) {
    int half = 1 << s;
    int up = lane & half;
    float ang = -(PI_F / (float)half) * (float)(lane & (half - 1));
    float ss, cc;
    __sincosf(ang, &ss, &cc);
    float2 tw = make_float2(cc, ss);
#pragma unroll
    for (int q = 0; q < 10; q++) {
      float2 oth;
      oth.x = __shfl_xor(v[q].x, half, 64);
      oth.y = __shfl_xor(v[q].y, half, 64);
      float2 sum = cadd(v[q], oth);
      float2 dif = cmul(csub(oth, v[q]), tw);
      v[q] = up ? dif : sum;
    }
  }
  return __brev(lane) >> 26;
}

// ---- stage A: ALL phases. Row FFTs, fp16 transposed output via LDS (1 barrier).
// grid = 5*16*80 = 6400 blocks x 256 (4 waves = 4 consecutive rows h) ----
__global__ __launch_bounds__(256) void stageA_kernel(const float* __restrict__ img,
                                                     uint32_t* __restrict__ AT) {
  __shared__ float2 lds[4 * 705];   // per-row stride 705 float2 (odd: breaks quad conflicts)
  int wv = threadIdx.x >> 6, lane = threadIdx.x & 63;
  int bx = blockIdx.x;
  int p = bx / (NIMG * 80);
  int rem = bx - p * (NIMG * 80);
  int i = rem / 80, hg = rem - i * 80;
  int h0 = hg * 4, h = h0 + wv;
  const float2* src = (const float2*)img + ((size_t)(p * NIMG + i) * NH + h) * NH;
  float ah = apodf(h) * (1.0f / 640.0f);  // fold 1/sqrt(Kh*Kw) ortho norm
  float2 b[5];
#pragma unroll
  for (int j = 0; j < 5; j++) {
    float2 x = src[lane + 64 * j];
    float sc = apodf(lane + 64 * j) * ah;
    b[j] = make_float2(x.x * sc, x.y * sc);
  }
  float2 v[10];
  int k2 = fft640_reg(b, v, lane);
  float2* rowl = lds + wv * 705 + 11 * k2;   // kw=k1+10*k2 stored at 11*k2+k1
#pragma unroll
  for (int k = 0; k < 10; k++) rowl[k] = v[k];
  __syncthreads();
  // cooperative transposed write: AT[kw][h0+c], quad of lanes = 16B contiguous
  int c = threadIdx.x & 3, kwb = threadIdx.x >> 2;
  uint32_t* dst = AT + (size_t)(p * NIMG + i) * NK * NH + h0 + c;
#pragma unroll
  for (int s = 0; s < 10; s++) {
    int kw = kwb + 64 * s;
    int q2 = (kw * 6554) >> 16;     // kw/10 (exact for kw<1638)
    int q1 = kw - 10 * q2;
    uint32_t hv = f2_to_h2(lds[c * 705 + 11 * q2 + q1]);
    __builtin_nontemporal_store(hv, dst + (size_t)kw * NH);
  }
}

// ---- stage B: column FFTs, pure-register, XCD-PINNED per image.
// grid = 2560 blocks x 256 per phase; bx = 8*J + x, x = XCD = i%8;
// J<160 -> image x, J>=160 -> image x+8. AT read nontemporal (don't evict G). ----
__global__ __launch_bounds__(256) void stageB_kernel(const uint32_t* __restrict__ AT,
                                                     uint32_t* __restrict__ G, int p) {
  int wv = threadIdx.x >> 6, lane = threadIdx.x & 63;
  int x = blockIdx.x & 7;
  int J = blockIdx.x >> 3;           // 0..319
  int i = x + 8 * (J >= 160);
  int kwg = (J >= 160) ? J - 160 : J;
  int kw = kwg * 4 + wv;
  const uint32_t* rowp = AT + ((size_t)(p * NIMG + i) * NK + kw) * NH;  // contiguous
  float2 b[5];
#pragma unroll
  for (int j = 0; j < 5; j++)
    b[j] = h2_to_f2(__builtin_nontemporal_load(rowp + lane + 64 * j));
  float2 v[10];
  int k2 = fft640_reg(b, v, lane);
  // lane writes 10 consecutive kh as 5 uint2 (pairs of half2); stays in L2
  uint32_t hv[10];
#pragma unroll
  for (int k = 0; k < 10; k++) hv[k] = f2_to_h2(v[k]);
  uint2* dst = (uint2*)(G + ((size_t)i * NK + kw) * NK + 10 * k2);
#pragma unroll
  for (int m = 0; m < 5; m++) dst[m] = make_uint2(hv[2 * m], hv[2 * m + 1]);
}

// ---- taps: per (phase, point): 6 weights+indices per dim + recentering phase.
// tapw stride 16 floats (64B, float4-loadable); tapi stride 12 ints (48B) ----
__global__ __launch_bounds__(256) void taps_kernel(const float* __restrict__ traj,
                                                   float* __restrict__ tapw,
                                                   int* __restrict__ tapi) {
  int t = blockIdx.x * 256 + threadIdx.x;
  if (t >= NPH * KLEN) return;
  int p = t / KLEN, l = t - p * KLEN;
  float inv_i0a = 1.0f / i0f(KB_ALPHA);
  float* wout = tapw + (size_t)t * 16;
  int* iout = tapi + (size_t)t * 12;
  float ang = 0.0f;
#pragma unroll
  for (int d = 0; d < 2; d++) {
    float om = traj[((size_t)p * 2 + d) * KLEN + l];
    float tt = om * 640.0f / 6.28318530717958647692f;
    float base = floorf(tt - 3.0f);
    ang += om * 160.0f;              // n_shift = 320//2
#pragma unroll
    for (int j = 0; j < 6; j++) {
      float kf = base + (float)(j + 1);
      float u = tt - kf;
      float arg = fmaxf(1.0f - (u * u) * (1.0f / 9.0f), 0.0f);
      wout[d * 6 + j] = i0f(KB_ALPHA * sqrtf(arg)) * inv_i0a;
      int ki = (int)kf + 640;        // kf in [-323,636] -> ki in [317,1276]
      if (ki >= 640) ki -= 640;
      iout[d * 6 + j] = ki;
    }
  }
  float s, c;
  sincosf(ang, &s, &c);              // accurate path: |ang| up to ~1005 rad
  wout[12] = c;
  wout[13] = s;
  wout[14] = 0.f;
  wout[15] = 0.f;
}

// ---- interp: XCD-pinned gather from L2-hot fp16 G. grid = 2000 blocks x 128.
// Same pinning as stageB -> image i's grid is hot in XCD i%8's L2.
// sched_barrier(0) keeps all 36 gathers in flight before the reduction. ----
__global__ __launch_bounds__(128) void interp_kernel(const uint32_t* __restrict__ G,
                                                     const float* __restrict__ tapw,
                                                     const int* __restrict__ tapi,
                                                     float* __restrict__ out, int p) {
  int x = blockIdx.x & 7;            // XCD (round-robin dispatch heuristic)
  int j = blockIdx.x >> 3;           // 0..249
  int i = x + 8 * (j >= 125);
  int jj = (j >= 125) ? j - 125 : j;
  int l = jj * 128 + threadIdx.x;
  // vectorized tap loads
  const float4* w4 = (const float4*)(tapw + (size_t)(p * KLEN + l) * 16);
  float4 wa = w4[0], wb = w4[1], wc = w4[2], wd = w4[3];
  const int4* i4 = (const int4*)(tapi + (size_t)(p * KLEN + l) * 12);
  int4 ia = i4[0], ib = i4[1], ic = i4[2];
  float whv[6] = {wa.x, wa.y, wa.z, wa.w, wb.x, wb.y};
  float wwv[6] = {wb.z, wb.w, wc.x, wc.y, wc.z, wc.w};
  int   ihv[6] = {ia.x, ia.y, ia.z, ia.w, ib.x, ib.y};
  int   iwv[6] = {ib.z, ib.w, ic.x, ic.y, ic.z, ic.w};
  const uint32_t* g = G + (size_t)i * NK * NK;
  // all 36 offsets, then all 36 loads in flight, then reduce
  int offs[36];
#pragma unroll
  for (int jw = 0; jw < 6; jw++) {
    int cb = iwv[jw] * NK;
#pragma unroll
    for (int jh = 0; jh < 6; jh++) offs[jw * 6 + jh] = cb + ihv[jh];
  }
  uint32_t raw[36];
#pragma unroll
  for (int t = 0; t < 36; t++) raw[t] = g[offs[t]];
  __builtin_amdgcn_sched_barrier(0);   // don't sink loads into the FMA chain
  float ar = 0.f, ai = 0.f;
#pragma unroll
  for (int jw = 0; jw < 6; jw++) {
    float sr = 0.f, si = 0.f;
#pragma unroll
    for (int jh = 0; jh < 6; jh++) {
      float2 v = h2_to_f2(raw[jw * 6 + jh]);
      sr = fmaf(whv[jh], v.x, sr);
      si = fmaf(whv[jh], v.y, si);
    }
    ar = fmaf(wwv[jw], sr, ar);
    ai = fmaf(wwv[jw], si, ai);
  }
  float c = wd.x, s = wd.y;
  size_t o = (size_t)(p * NIMG + i) * KLEN + l;
  ((float2*)out)[o] = make_float2(ar * c - ai * s, ar * s + ai * c);
}

extern "C" void kernel_launch(void* const* d_in, const int* in_sizes, int n_in,
                              void* d_out, int out_size, void* d_ws, size_t ws_size,
                              hipStream_t stream) {
  const float* img  = (const float*)d_in[0];   // (1,5,8,2,320,320,2) f32
  const float* traj = (const float*)d_in[1];   // (5,2,16000) f32
  float* out = (float*)d_out;                  // (1,5,8,2,16000,2) f32

  char* ws = (char*)d_ws;
  float*    tapw = (float*)ws;                       // 5*16000*16*4 = 5,120,000 B
  int*      tapi = (int*)(ws + 5120000);             // 5*16000*12*4 = 3,840,000 B
  uint32_t* AT   = (uint32_t*)(ws + 8960000);        // 80*640*320*4 = 65,536,000 B (fp16)
  uint32_t* G    = (uint32_t*)(ws + 8960000 + 65536000);  // 16*640*640*4 = 26,214,400 B (fp16)
  // total 100.7 MB

  taps_kernel<<<(NPH * KLEN + 255) / 256, 256, 0, stream>>>(traj, tapw, tapi);
  stageA_kernel<<<NPH * NIMG * 80, 256, 0, stream>>>(img, AT);
  for (int p = 0; p < NPH; p++) {
    stageB_kernel<<<NIMG * 160, 256, 0, stream>>>(AT, G, p);
    interp_kernel<<<2000, 128, 0, stream>>>(G, tapw, tapi, out, p);
  }
}

// Round 7
// 362.206 us; speedup vs baseline: 2.5230x; 1.2330x over previous
//
#include <hip/hip_runtime.h>
#include <hip/hip_fp16.h>
#include <cstdint>
#include <cstddef>

// NUFFT type-2, torchkbnufft-compatible (J=6, alpha=14.04, os=2).
// Pipeline (5 phases, 16 coil-images each, 320x320 -> 640x640):
//   taps:   KB weights/indices/phase per (phase,point)
//   stageA: ALL phases, apodize+pad rows, reg-FFT-640 along W -> AT[pi][kw][h] fp16.
//           16 rows/block (4 waves x 4 sequential FFTs) staged in LDS as fp16.
//           Row stride ASTR=709: in-row layout 11*k2+k1 needs 703 slots (R6 bug:
//           stride 645 overflowed into the next row -> absmax 2.1). 11*k2 mod 32
//           bijective -> 2-way store = free. Transposed write emits 16 consecutive
//           h per kw = full 64B lines (R5 had 2x write amplification).
//   per phase p:
//     stageB: reg-FFT-640 along H -> G[i][kw][kh] fp16, XCD-PINNED per image
//             (image i on XCD i%8; 1.64MB grid stays in that XCD's 4MB L2)
//     interp: 6x6 KB gather, XCD-pinned to the SAME XCD -> gathers hit hot L2;
//             sched_barrier(0) keeps all 36 gathers in flight.
// FFT-640 = four-step 10x64 in registers: zero-padded FFT-10 (2x FFT-5), twiddle,
// 6 __shfl_xor butterfly stages. fp16 storage: rel err ~5e-4 << 4.06e-2 threshold.

#define PI_F     3.14159265358979323846f
#define KB_ALPHA 14.04f
#define NPH  5
#define NIMG 16
#define NH   320
#define NK   640
#define KLEN 16000

__device__ __forceinline__ uint32_t f2_to_h2(float2 v) {
  union { __half2 h; uint32_t u; } cv;
  cv.h = __float22half2_rn(v);
  return cv.u;
}
__device__ __forceinline__ float2 h2_to_f2(uint32_t u) {
  union { uint32_t u; __half2 h; } cv;
  cv.u = u;
  return __half22float2(cv.h);
}

// ---- modified Bessel I0 (A&S 9.8.1 / 9.8.2, rel err ~2e-7). I0(alpha) cancels
// between apodization (numerator) and tap weights (denominator). ----
__device__ __forceinline__ float i0f(float x) {
  if (x < 3.75f) {
    float t = x * (1.0f / 3.75f), t2 = t * t;
    return 1.0f + t2 * (3.5156229f + t2 * (3.0899424f + t2 * (1.2067492f +
                 t2 * (0.2659732f + t2 * (0.0360768f + t2 * 0.0045813f)))));
  }
  float t = 3.75f / x;
  float poly = 0.39894228f + t * (0.01328592f + t * (0.00225319f + t * (-0.00157565f +
               t * (0.00916281f + t * (-0.02057706f + t * (0.02635537f +
               t * (-0.01647633f + t * 0.00392377f)))))));
  return expf(x) * rsqrtf(x) * poly;
}

// apodization scale (1/FT(KB)); z^2 = alpha^2-(pi*J*u)^2 > 0 always for |u|<=0.25
__device__ __forceinline__ float apodf(int n) {
  float u = (float)(n - 160) * (1.0f / 640.0f);
  float pj = PI_F * 6.0f * u;
  float z = sqrtf(KB_ALPHA * KB_ALPHA - pj * pj);
  float sh = 0.5f * (expf(z) - expf(-z));     // sinh(z)
  return z * i0f(KB_ALPHA) / (6.0f * sh);     // 1/ft = z*I0a/(J*sinh z)
}

__device__ __forceinline__ float2 cadd(float2 a, float2 b) { return make_float2(a.x + b.x, a.y + b.y); }
__device__ __forceinline__ float2 csub(float2 a, float2 b) { return make_float2(a.x - b.x, a.y - b.y); }
__device__ __forceinline__ float2 cmul(float2 a, float2 b) {
  return make_float2(fmaf(a.x, b.x, -a.y * b.y), fmaf(a.x, b.y, a.y * b.x));
}
__device__ __forceinline__ float2 cxmad(float2 a, float2 w, float2 x) {
  a.x = fmaf(w.x, x.x, fmaf(-w.y, x.y, a.x));
  a.y = fmaf(w.x, x.y, fmaf( w.y, x.x, a.y));
  return a;
}

// direct 5-point DFT, forward (W5 = e^{-2pi i/5})
__device__ __forceinline__ void fft5(const float2 b[5], float2 z[5]) {
  const float2 w1 = make_float2( 0.309016994374947424f, -0.951056516295153572f);
  const float2 w2 = make_float2(-0.809016994374947424f, -0.587785252292473129f);
  const float2 w3 = make_float2(-0.809016994374947424f,  0.587785252292473129f);
  const float2 w4 = make_float2( 0.309016994374947424f,  0.951056516295153572f);
  z[0] = cadd(cadd(b[0], b[1]), cadd(cadd(b[2], b[3]), b[4]));
  z[1] = b[0]; z[1] = cxmad(z[1], w1, b[1]); z[1] = cxmad(z[1], w2, b[2]); z[1] = cxmad(z[1], w3, b[3]); z[1] = cxmad(z[1], w4, b[4]);
  z[2] = b[0]; z[2] = cxmad(z[2], w2, b[1]); z[2] = cxmad(z[2], w4, b[2]); z[2] = cxmad(z[2], w1, b[3]); z[2] = cxmad(z[2], w3, b[4]);
  z[3] = b[0]; z[3] = cxmad(z[3], w3, b[1]); z[3] = cxmad(z[3], w1, b[2]); z[3] = cxmad(z[3], w4, b[3]); z[3] = cxmad(z[3], w2, b[4]);
  z[4] = b[0]; z[4] = cxmad(z[4], w4, b[1]); z[4] = cxmad(z[4], w3, b[2]); z[4] = cxmad(z[4], w2, b[3]); z[4] = cxmad(z[4], w1, b[4]);
}

// Register FFT-640 of the zero-padded sequence x[64*n1 + lane] = b[n1] (n1=0..4;
// n1=5..9 implicitly zero). Returns k2 = bitrev6(lane); v[k1] = X[k1 + 10*k2].
__device__ __forceinline__ int fft640_reg(const float2 b[5], float2 v[10], int lane) {
  // FFT-10 with upper half zero: even outputs FFT5(b), odd outputs FFT5(b .* W10^n)
  const float2 t1 = make_float2( 0.809016994374947424f, -0.587785252292473129f); // W10^1
  const float2 t2 = make_float2( 0.309016994374947424f, -0.951056516295153572f); // W10^2
  const float2 t3 = make_float2(-0.309016994374947424f, -0.951056516295153572f); // W10^3
  const float2 t4 = make_float2(-0.809016994374947424f, -0.587785252292473129f); // W10^4
  float2 e[5], o[5], bp[5];
  fft5(b, e);
  bp[0] = b[0]; bp[1] = cmul(b[1], t1); bp[2] = cmul(b[2], t2);
  bp[3] = cmul(b[3], t3); bp[4] = cmul(b[4], t4);
  fft5(bp, o);
  v[0] = e[0]; v[2] = e[1]; v[4] = e[2]; v[6] = e[3]; v[8] = e[4];
  v[1] = o[0]; v[3] = o[1]; v[5] = o[2]; v[7] = o[3]; v[9] = o[4];
  // twiddle: v[k1] *= W640^{lane*k1}
  float sn, cs;
  __sincosf(-2.0f * PI_F * (float)lane * (1.0f / 640.0f), &sn, &cs);
  float2 w1 = make_float2(cs, sn), wk = w1;
  v[1] = cmul(v[1], wk);
#pragma unroll
  for (int k = 2; k < 10; k++) { wk = cmul(wk, w1); v[k] = cmul(v[k], wk); }
  // cross-lane FFT-64 over n2=lane: DIF radix-2, 6 shuffle stages, bitrev output
#pragma unroll
  for (int s = 5; s >= 0; s--) {
    int half = 1 << s;
    int up = lane & half;
    float ang = -(PI_F / (float)half) * (float)(lane & (half - 1));
    float ss, cc;
    __sincosf(ang, &ss, &cc);
    float2 tw = make_float2(cc, ss);
#pragma unroll
    for (int q = 0; q < 10; q++) {
      float2 oth;
      oth.x = __shfl_xor(v[q].x, half, 64);
      oth.y = __shfl_xor(v[q].y, half, 64);
      float2 sum = cadd(v[q], oth);
      float2 dif = cmul(csub(oth, v[q]), tw);
      v[q] = up ? dif : sum;
    }
  }
  return __brev(lane) >> 26;
}

// ---- stage A: ALL phases. 16 rows/block; 4 waves x 4 sequential row-FFTs,
// fp16 LDS staging (stride 709 >= 703 required by 11*k2+k1 layout),
// transposed write = full 64B lines. grid = 5*16*20 = 1600 blocks x 256 ----
#define ASTR 709
__global__ __launch_bounds__(256) void stageA_kernel(const float* __restrict__ img,
                                                     uint32_t* __restrict__ AT) {
  __shared__ uint32_t lds[16 * ASTR];   // 45,376 B fp16-pairs
  int wv = threadIdx.x >> 6, lane = threadIdx.x & 63;
  int bx = blockIdx.x;
  int p = bx / (NIMG * 20);
  int rem = bx - p * (NIMG * 20);
  int i = rem / 20, hg = rem - i * 20;
  int h0 = hg * 16;
  const float2* base = (const float2*)img + (size_t)(p * NIMG + i) * NH * NH;
  // w-apodization is row-invariant: compute the 5 lane scales once
  float aw[5];
#pragma unroll
  for (int j = 0; j < 5; j++) aw[j] = apodf(lane + 64 * j) * (1.0f / 640.0f);
  // 4 sequential row FFTs per wave: rows r = wv*4 + t
#pragma unroll 1
  for (int t = 0; t < 4; t++) {
    int r = wv * 4 + t;
    int h = h0 + r;
    const float2* src = base + (size_t)h * NH;
    float ah = apodf(h);
    float2 b[5];
#pragma unroll
    for (int j = 0; j < 5; j++) {
      float2 x = src[lane + 64 * j];
      float sc = aw[j] * ah;
      b[j] = make_float2(x.x * sc, x.y * sc);
    }
    float2 v[10];
    int k2 = fft640_reg(b, v, lane);
    uint32_t* rowl = lds + r * ASTR + 11 * k2;   // kw=k1+10*k2 at 11*k2+k1 (max 702 < 709)
#pragma unroll
    for (int k = 0; k < 10; k++) rowl[k] = f2_to_h2(v[k]);
  }
  __syncthreads();
  // transposed write: AT[kw][h0+c], c = tid&15 -> 16 consecutive h = 64B line
  int c = threadIdx.x & 15, kwv = threadIdx.x >> 4;
  uint32_t* dst = AT + (size_t)(p * NIMG + i) * NK * NH + h0 + c;
  const uint32_t* srcl = lds + c * ASTR;
#pragma unroll
  for (int s = 0; s < 40; s++) {
    int kw = kwv + 16 * s;
    int q2 = (kw * 6554) >> 16;     // kw/10 (exact for kw<1638)
    int q1 = kw - 10 * q2;
    __builtin_nontemporal_store(srcl[11 * q2 + q1], dst + (size_t)kw * NH);
  }
}

// ---- stage B: column FFTs, pure-register, XCD-PINNED per image.
// grid = 2560 blocks x 256 per phase; bx = 8*J + x, x = XCD = i%8;
// J<160 -> image x, J>=160 -> image x+8. AT read nontemporal (don't evict G). ----
__global__ __launch_bounds__(256) void stageB_kernel(const uint32_t* __restrict__ AT,
                                                     uint32_t* __restrict__ G, int p) {
  int wv = threadIdx.x >> 6, lane = threadIdx.x & 63;
  int x = blockIdx.x & 7;
  int J = blockIdx.x >> 3;           // 0..319
  int i = x + 8 * (J >= 160);
  int kwg = (J >= 160) ? J - 160 : J;
  int kw = kwg * 4 + wv;
  const uint32_t* rowp = AT + ((size_t)(p * NIMG + i) * NK + kw) * NH;  // contiguous
  float2 b[5];
#pragma unroll
  for (int j = 0; j < 5; j++)
    b[j] = h2_to_f2(__builtin_nontemporal_load(rowp + lane + 64 * j));
  float2 v[10];
  int k2 = fft640_reg(b, v, lane);
  // lane writes 10 consecutive kh as 5 uint2 (pairs of half2); stays in L2
  uint32_t hv[10];
#pragma unroll
  for (int k = 0; k < 10; k++) hv[k] = f2_to_h2(v[k]);
  uint2* dst = (uint2*)(G + ((size_t)i * NK + kw) * NK + 10 * k2);
#pragma unroll
  for (int m = 0; m < 5; m++) dst[m] = make_uint2(hv[2 * m], hv[2 * m + 1]);
}

// ---- taps: per (phase, point): 6 weights+indices per dim + recentering phase.
// tapw stride 16 floats (64B, float4-loadable); tapi stride 12 ints (48B) ----
__global__ __launch_bounds__(256) void taps_kernel(const float* __restrict__ traj,
                                                   float* __restrict__ tapw,
                                                   int* __restrict__ tapi) {
  int t = blockIdx.x * 256 + threadIdx.x;
  if (t >= NPH * KLEN) return;
  int p = t / KLEN, l = t - p * KLEN;
  float inv_i0a = 1.0f / i0f(KB_ALPHA);
  float* wout = tapw + (size_t)t * 16;
  int* iout = tapi + (size_t)t * 12;
  float ang = 0.0f;
#pragma unroll
  for (int d = 0; d < 2; d++) {
    float om = traj[((size_t)p * 2 + d) * KLEN + l];
    float tt = om * 640.0f / 6.28318530717958647692f;
    float base = floorf(tt - 3.0f);
    ang += om * 160.0f;              // n_shift = 320//2
#pragma unroll
    for (int j = 0; j < 6; j++) {
      float kf = base + (float)(j + 1);
      float u = tt - kf;
      float arg = fmaxf(1.0f - (u * u) * (1.0f / 9.0f), 0.0f);
      wout[d * 6 + j] = i0f(KB_ALPHA * sqrtf(arg)) * inv_i0a;
      int ki = (int)kf + 640;        // kf in [-323,636] -> ki in [317,1276]
      if (ki >= 640) ki -= 640;
      iout[d * 6 + j] = ki;
    }
  }
  float s, c;
  sincosf(ang, &s, &c);              // accurate path: |ang| up to ~1005 rad
  wout[12] = c;
  wout[13] = s;
  wout[14] = 0.f;
  wout[15] = 0.f;
}

// ---- interp: XCD-pinned gather from L2-hot fp16 G. grid = 2000 blocks x 128.
// Same pinning as stageB -> image i's grid is hot in XCD i%8's L2.
// sched_barrier(0) keeps all 36 gathers in flight before the reduction. ----
__global__ __launch_bounds__(128) void interp_kernel(const uint32_t* __restrict__ G,
                                                     const float* __restrict__ tapw,
                                                     const int* __restrict__ tapi,
                                                     float* __restrict__ out, int p) {
  int x = blockIdx.x & 7;            // XCD (round-robin dispatch heuristic)
  int j = blockIdx.x >> 3;           // 0..249
  int i = x + 8 * (j >= 125);
  int jj = (j >= 125) ? j - 125 : j;
  int l = jj * 128 + threadIdx.x;
  // vectorized tap loads
  const float4* w4 = (const float4*)(tapw + (size_t)(p * KLEN + l) * 16);
  float4 wa = w4[0], wb = w4[1], wc = w4[2], wd = w4[3];
  const int4* i4 = (const int4*)(tapi + (size_t)(p * KLEN + l) * 12);
  int4 ia = i4[0], ib = i4[1], ic = i4[2];
  float whv[6] = {wa.x, wa.y, wa.z, wa.w, wb.x, wb.y};
  float wwv[6] = {wb.z, wb.w, wc.x, wc.y, wc.z, wc.w};
  int   ihv[6] = {ia.x, ia.y, ia.z, ia.w, ib.x, ib.y};
  int   iwv[6] = {ib.z, ib.w, ic.x, ic.y, ic.z, ic.w};
  const uint32_t* g = G + (size_t)i * NK * NK;
  // all 36 offsets, then all 36 loads in flight, then reduce
  int offs[36];
#pragma unroll
  for (int jw = 0; jw < 6; jw++) {
    int cb = iwv[jw] * NK;
#pragma unroll
    for (int jh = 0; jh < 6; jh++) offs[jw * 6 + jh] = cb + ihv[jh];
  }
  uint32_t raw[36];
#pragma unroll
  for (int t = 0; t < 36; t++) raw[t] = g[offs[t]];
  __builtin_amdgcn_sched_barrier(0);   // don't sink loads into the FMA chain
  float ar = 0.f, ai = 0.f;
#pragma unroll
  for (int jw = 0; jw < 6; jw++) {
    float sr = 0.f, si = 0.f;
#pragma unroll
    for (int jh = 0; jh < 6; jh++) {
      float2 v = h2_to_f2(raw[jw * 6 + jh]);
      sr = fmaf(whv[jh], v.x, sr);
      si = fmaf(whv[jh], v.y, si);
    }
    ar = fmaf(wwv[jw], sr, ar);
    ai = fmaf(wwv[jw], si, ai);
  }
  float c = wd.x, s = wd.y;
  size_t o = (size_t)(p * NIMG + i) * KLEN + l;
  ((float2*)out)[o] = make_float2(ar * c - ai * s, ar * s + ai * c);
}

extern "C" void kernel_launch(void* const* d_in, const int* in_sizes, int n_in,
                              void* d_out, int out_size, void* d_ws, size_t ws_size,
                              hipStream_t stream) {
  const float* img  = (const float*)d_in[0];   // (1,5,8,2,320,320,2) f32
  const float* traj = (const float*)d_in[1];   // (5,2,16000) f32
  float* out = (float*)d_out;                  // (1,5,8,2,16000,2) f32

  char* ws = (char*)d_ws;
  float*    tapw = (float*)ws;                       // 5*16000*16*4 = 5,120,000 B
  int*      tapi = (int*)(ws + 5120000);             // 5*16000*12*4 = 3,840,000 B
  uint32_t* AT   = (uint32_t*)(ws + 8960000);        // 80*640*320*4 = 65,536,000 B (fp16)
  uint32_t* G    = (uint32_t*)(ws + 8960000 + 65536000);  // 16*640*640*4 = 26,214,400 B (fp16)
  // total 100.7 MB

  taps_kernel<<<(NPH * KLEN + 255) / 256, 256, 0, stream>>>(traj, tapw, tapi);
  stageA_kernel<<<NPH * NIMG * 20, 256, 0, stream>>>(img, AT);
  for (int p = 0; p < NPH; p++) {
    stageB_kernel<<<NIMG * 160, 256, 0, stream>>>(AT, G, p);
    interp_kernel<<<2000, 128, 0, stream>>>(G, tapw, tapi, out, p);
  }
}

// Round 9
// 361.013 us; speedup vs baseline: 2.5314x; 1.0033x over previous
//
#include <hip/hip_runtime.h>
#include <hip/hip_fp16.h>
#include <cstdint>
#include <cstddef>

// NUFFT type-2, torchkbnufft-compatible (J=6, alpha=14.04, os=2).
// Pipeline (5 phases, 16 coil-images each, 320x320 -> 640x640):
//   taps:   KB weights/indices/phase per (phase,point)
//   stageA: ALL phases, apodize+pad rows, reg-FFT-640 along W -> AT[pi][kw][h] fp16.
//           256-thread blocks (R7-proven): 16 rows/block, 4 waves x 4 FFTs, LDS
//           stride 709 (>=703 needed by 11*k2+k1 layout). Transposed write: 16
//           consecutive h = 64B lines. NO nontemporal hints (R8 replay-divergence
//           suspect: NT cache-policy store/load pair was the only non-default
//           coherency feature; dropped for determinism).
//   per phase p:
//     stageB: reg-FFT-640 along H -> G_p[i][kw][kh] fp16, XCD-PINNED per image
//             (image i on XCD i%8; 1.64MB grid stays in that XCD's 4MB L2).
//             PER-PHASE G buffer: interp(p) never reads what stageB(p+1) writes,
//             so correctness doesn't depend on graph-capture edge fidelity.
//     interp: 6x6 KB gather, XCD-pinned to the SAME XCD -> gathers hit hot L2;
//             sched_barrier(0) keeps all 36 gathers in flight.
// FFT-640 = four-step 10x64 in registers: zero-padded FFT-10 (2x FFT-5), twiddle,
// 6 __shfl_xor butterfly stages. Butterfly uses sign-fold + lane-conditional
// twiddle (exact identity (1,0) on lower lanes): 6 VALU/pt/stage vs 10 naive,
// final stage add/sub only. fp16 storage: rel err ~5e-4 << 4.06e-2 threshold.

#define PI_F     3.14159265358979323846f
#define KB_ALPHA 14.04f
#define NPH  5
#define NIMG 16
#define NH   320
#define NK   640
#define KLEN 16000

__device__ __forceinline__ uint32_t f2_to_h2(float2 v) {
  union { __half2 h; uint32_t u; } cv;
  cv.h = __float22half2_rn(v);
  return cv.u;
}
__device__ __forceinline__ float2 h2_to_f2(uint32_t u) {
  union { uint32_t u; __half2 h; } cv;
  cv.u = u;
  return __half22float2(cv.h);
}

// ---- modified Bessel I0 (A&S 9.8.1 / 9.8.2, rel err ~2e-7). I0(alpha) cancels
// between apodization (numerator) and tap weights (denominator). ----
__device__ __forceinline__ float i0f(float x) {
  if (x < 3.75f) {
    float t = x * (1.0f / 3.75f), t2 = t * t;
    return 1.0f + t2 * (3.5156229f + t2 * (3.0899424f + t2 * (1.2067492f +
                 t2 * (0.2659732f + t2 * (0.0360768f + t2 * 0.0045813f)))));
  }
  float t = 3.75f / x;
  float poly = 0.39894228f + t * (0.01328592f + t * (0.00225319f + t * (-0.00157565f +
               t * (0.00916281f + t * (-0.02057706f + t * (0.02635537f +
               t * (-0.01647633f + t * 0.00392377f)))))));
  return expf(x) * rsqrtf(x) * poly;
}

// apodization scale (1/FT(KB)); z^2 = alpha^2-(pi*J*u)^2 > 0 always for |u|<=0.25
__device__ __forceinline__ float apodf(int n) {
  float u = (float)(n - 160) * (1.0f / 640.0f);
  float pj = PI_F * 6.0f * u;
  float z = sqrtf(KB_ALPHA * KB_ALPHA - pj * pj);
  float sh = 0.5f * (expf(z) - expf(-z));     // sinh(z)
  return z * i0f(KB_ALPHA) / (6.0f * sh);     // 1/ft = z*I0a/(J*sinh z)
}

__device__ __forceinline__ float2 cadd(float2 a, float2 b) { return make_float2(a.x + b.x, a.y + b.y); }
__device__ __forceinline__ float2 cmul(float2 a, float2 b) {
  return make_float2(fmaf(a.x, b.x, -a.y * b.y), fmaf(a.x, b.y, a.y * b.x));
}
__device__ __forceinline__ float2 cxmad(float2 a, float2 w, float2 x) {
  a.x = fmaf(w.x, x.x, fmaf(-w.y, x.y, a.x));
  a.y = fmaf(w.x, x.y, fmaf( w.y, x.x, a.y));
  return a;
}

// direct 5-point DFT, forward (W5 = e^{-2pi i/5})
__device__ __forceinline__ void fft5(const float2 b[5], float2 z[5]) {
  const float2 w1 = make_float2( 0.309016994374947424f, -0.951056516295153572f);
  const float2 w2 = make_float2(-0.809016994374947424f, -0.587785252292473129f);
  const float2 w3 = make_float2(-0.809016994374947424f,  0.587785252292473129f);
  const float2 w4 = make_float2( 0.309016994374947424f,  0.951056516295153572f);
  z[0] = cadd(cadd(b[0], b[1]), cadd(cadd(b[2], b[3]), b[4]));
  z[1] = b[0]; z[1] = cxmad(z[1], w1, b[1]); z[1] = cxmad(z[1], w2, b[2]); z[1] = cxmad(z[1], w3, b[3]); z[1] = cxmad(z[1], w4, b[4]);
  z[2] = b[0]; z[2] = cxmad(z[2], w2, b[1]); z[2] = cxmad(z[2], w4, b[2]); z[2] = cxmad(z[2], w1, b[3]); z[2] = cxmad(z[2], w3, b[4]);
  z[3] = b[0]; z[3] = cxmad(z[3], w3, b[1]); z[3] = cxmad(z[3], w1, b[2]); z[3] = cxmad(z[3], w4, b[3]); z[3] = cxmad(z[3], w2, b[4]);
  z[4] = b[0]; z[4] = cxmad(z[4], w4, b[1]); z[4] = cxmad(z[4], w3, b[2]); z[4] = cxmad(z[4], w2, b[3]); z[4] = cxmad(z[4], w1, b[4]);
}

// Register FFT-640 of the zero-padded sequence x[64*n1 + lane] = b[n1] (n1=0..4;
// n1=5..9 implicitly zero). Returns k2 = bitrev6(lane); v[k1] = X[k1 + 10*k2].
__device__ __forceinline__ int fft640_reg(const float2 b[5], float2 v[10], int lane) {
  // FFT-10 with upper half zero: even outputs FFT5(b), odd outputs FFT5(b .* W10^n)
  const float2 t1 = make_float2( 0.809016994374947424f, -0.587785252292473129f); // W10^1
  const float2 t2 = make_float2( 0.309016994374947424f, -0.951056516295153572f); // W10^2
  const float2 t3 = make_float2(-0.309016994374947424f, -0.951056516295153572f); // W10^3
  const float2 t4 = make_float2(-0.809016994374947424f, -0.587785252292473129f); // W10^4
  float2 e[5], o[5], bp[5];
  fft5(b, e);
  bp[0] = b[0]; bp[1] = cmul(b[1], t1); bp[2] = cmul(b[2], t2);
  bp[3] = cmul(b[3], t3); bp[4] = cmul(b[4], t4);
  fft5(bp, o);
  v[0] = e[0]; v[2] = e[1]; v[4] = e[2]; v[6] = e[3]; v[8] = e[4];
  v[1] = o[0]; v[3] = o[1]; v[5] = o[2]; v[7] = o[3]; v[9] = o[4];
  // twiddle: v[k1] *= W640^{lane*k1}
  float sn, cs;
  __sincosf(-2.0f * PI_F * (float)lane * (1.0f / 640.0f), &sn, &cs);
  float2 w1 = make_float2(cs, sn), wk = w1;
  v[1] = cmul(v[1], wk);
#pragma unroll
  for (int k = 2; k < 10; k++) { wk = cmul(wk, w1); v[k] = cmul(v[k], wk); }
  // cross-lane FFT-64 over n2=lane: DIF radix-2, 6 shuffle stages, bitrev output.
  // Butterfly: t = sgn*v + oth (up: oth-v, low: v+oth), then *twl where twl is
  // the stage twiddle on upper lanes and exactly (1,0) on lower lanes.
#pragma unroll
  for (int s = 5; s >= 1; s--) {
    int half = 1 << s;
    int up = lane & half;
    float ang = -(PI_F / (float)half) * (float)(lane & (half - 1));
    float ss, cc;
    __sincosf(ang, &ss, &cc);
    float sgn = up ? -1.0f : 1.0f;
    float2 twl = make_float2(up ? cc : 1.0f, up ? ss : 0.0f);
#pragma unroll
    for (int q = 0; q < 10; q++) {
      float2 oth;
      oth.x = __shfl_xor(v[q].x, half, 64);
      oth.y = __shfl_xor(v[q].y, half, 64);
      float2 t = make_float2(fmaf(sgn, v[q].x, oth.x), fmaf(sgn, v[q].y, oth.y));
      v[q] = cmul(t, twl);
    }
  }
  {  // final stage half=1: twiddle is identity everywhere — adds/subs only
    float sgn = (lane & 1) ? -1.0f : 1.0f;
#pragma unroll
    for (int q = 0; q < 10; q++) {
      float2 oth;
      oth.x = __shfl_xor(v[q].x, 1, 64);
      oth.y = __shfl_xor(v[q].y, 1, 64);
      v[q] = make_float2(fmaf(sgn, v[q].x, oth.x), fmaf(sgn, v[q].y, oth.y));
    }
  }
  return __brev(lane) >> 26;
}

// ---- stage A: ALL phases. 16 rows/block; 4 waves x 4 sequential row-FFTs,
// fp16 LDS staging (stride 709 >= 703 required by 11*k2+k1 layout),
// transposed write = full 64B lines. grid = 5*16*20 = 1600 blocks x 256 ----
#define ASTR 709
__global__ __launch_bounds__(256) void stageA_kernel(const float* __restrict__ img,
                                                     uint32_t* __restrict__ AT) {
  __shared__ uint32_t lds[16 * ASTR];   // 45,376 B fp16-pairs
  int wv = threadIdx.x >> 6, lane = threadIdx.x & 63;
  int bx = blockIdx.x;
  int p = bx / (NIMG * 20);
  int rem = bx - p * (NIMG * 20);
  int i = rem / 20, hg = rem - i * 20;
  int h0 = hg * 16;
  const float2* base = (const float2*)img + (size_t)(p * NIMG + i) * NH * NH;
  // w-apodization is row-invariant: compute the 5 lane scales once
  float aw[5];
#pragma unroll
  for (int j = 0; j < 5; j++) aw[j] = apodf(lane + 64 * j) * (1.0f / 640.0f);
  // 4 sequential row FFTs per wave: rows r = wv*4 + t
#pragma unroll 1
  for (int t = 0; t < 4; t++) {
    int r = wv * 4 + t;
    int h = h0 + r;
    const float2* src = base + (size_t)h * NH;
    float ah = apodf(h);
    float2 b[5];
#pragma unroll
    for (int j = 0; j < 5; j++) {
      float2 x = src[lane + 64 * j];
      float sc = aw[j] * ah;
      b[j] = make_float2(x.x * sc, x.y * sc);
    }
    float2 v[10];
    int k2 = fft640_reg(b, v, lane);
    uint32_t* rowl = lds + r * ASTR + 11 * k2;   // kw=k1+10*k2 at 11*k2+k1 (max 702 < 709)
#pragma unroll
    for (int k = 0; k < 10; k++) rowl[k] = f2_to_h2(v[k]);
  }
  __syncthreads();
  // transposed write: AT[kw][h0+c], c = tid&15 -> 16 consecutive h = 64B line
  int c = threadIdx.x & 15, kwv = threadIdx.x >> 4;   // kwv in [0,16)
  uint32_t* dst = AT + (size_t)(p * NIMG + i) * NK * NH + h0 + c;
  const uint32_t* srcl = lds + c * ASTR;
#pragma unroll
  for (int s = 0; s < 40; s++) {
    int kw = kwv + 16 * s;
    int q2 = (kw * 6554) >> 16;     // kw/10 (exact for kw<1638)
    int q1 = kw - 10 * q2;
    dst[(size_t)kw * NH] = srcl[11 * q2 + q1];
  }
}

// ---- stage B: column FFTs, pure-register, XCD-PINNED per image.
// grid = 2560 blocks x 256 per phase; bx = 8*J + x, x = XCD = i%8;
// J<160 -> image x, J>=160 -> image x+8. ----
__global__ __launch_bounds__(256) void stageB_kernel(const uint32_t* __restrict__ AT,
                                                     uint32_t* __restrict__ G, int p) {
  int wv = threadIdx.x >> 6, lane = threadIdx.x & 63;
  int x = blockIdx.x & 7;
  int J = blockIdx.x >> 3;           // 0..319
  int i = x + 8 * (J >= 160);
  int kwg = (J >= 160) ? J - 160 : J;
  int kw = kwg * 4 + wv;
  const uint32_t* rowp = AT + ((size_t)(p * NIMG + i) * NK + kw) * NH;  // contiguous
  float2 b[5];
#pragma unroll
  for (int j = 0; j < 5; j++) b[j] = h2_to_f2(rowp[lane + 64 * j]);
  float2 v[10];
  int k2 = fft640_reg(b, v, lane);
  // lane writes 10 consecutive kh as 5 uint2 (pairs of half2); stays in L2
  uint32_t hv[10];
#pragma unroll
  for (int k = 0; k < 10; k++) hv[k] = f2_to_h2(v[k]);
  uint2* dst = (uint2*)(G + ((size_t)i * NK + kw) * NK + 10 * k2);
#pragma unroll
  for (int m = 0; m < 5; m++) dst[m] = make_uint2(hv[2 * m], hv[2 * m + 1]);
}

// ---- taps: per (phase, point): 6 weights+indices per dim + recentering phase.
// tapw stride 16 floats (64B, float4-loadable); tapi stride 12 ints (48B) ----
__global__ __launch_bounds__(256) void taps_kernel(const float* __restrict__ traj,
                                                   float* __restrict__ tapw,
                                                   int* __restrict__ tapi) {
  int t = blockIdx.x * 256 + threadIdx.x;
  if (t >= NPH * KLEN) return;
  int p = t / KLEN, l = t - p * KLEN;
  float inv_i0a = 1.0f / i0f(KB_ALPHA);
  float* wout = tapw + (size_t)t * 16;
  int* iout = tapi + (size_t)t * 12;
  float ang = 0.0f;
#pragma unroll
  for (int d = 0; d < 2; d++) {
    float om = traj[((size_t)p * 2 + d) * KLEN + l];
    float tt = om * 640.0f / 6.28318530717958647692f;
    float base = floorf(tt - 3.0f);
    ang += om * 160.0f;              // n_shift = 320//2
#pragma unroll
    for (int j = 0; j < 6; j++) {
      float kf = base + (float)(j + 1);
      float u = tt - kf;
      float arg = fmaxf(1.0f - (u * u) * (1.0f / 9.0f), 0.0f);
      wout[d * 6 + j] = i0f(KB_ALPHA * sqrtf(arg)) * inv_i0a;
      int ki = (int)kf + 640;        // kf in [-323,636] -> ki in [317,1276]
      if (ki >= 640) ki -= 640;
      iout[d * 6 + j] = ki;
    }
  }
  float s, c;
  sincosf(ang, &s, &c);              // accurate path: |ang| up to ~1005 rad
  wout[12] = c;
  wout[13] = s;
  wout[14] = 0.f;
  wout[15] = 0.f;
}

// ---- interp: XCD-pinned gather from L2-hot fp16 G. grid = 2000 blocks x 128.
// Same pinning as stageB -> image i's grid is hot in XCD i%8's L2.
// sched_barrier(0) keeps all 36 gathers in flight before the reduction. ----
__global__ __launch_bounds__(128) void interp_kernel(const uint32_t* __restrict__ G,
                                                     const float* __restrict__ tapw,
                                                     const int* __restrict__ tapi,
                                                     float* __restrict__ out, int p) {
  int x = blockIdx.x & 7;            // XCD (round-robin dispatch heuristic)
  int j = blockIdx.x >> 3;           // 0..249
  int i = x + 8 * (j >= 125);
  int jj = (j >= 125) ? j - 125 : j;
  int l = jj * 128 + threadIdx.x;
  // vectorized tap loads
  const float4* w4 = (const float4*)(tapw + (size_t)(p * KLEN + l) * 16);
  float4 wa = w4[0], wb = w4[1], wc = w4[2], wd = w4[3];
  const int4* i4 = (const int4*)(tapi + (size_t)(p * KLEN + l) * 12);
  int4 ia = i4[0], ib = i4[1], ic = i4[2];
  float whv[6] = {wa.x, wa.y, wa.z, wa.w, wb.x, wb.y};
  float wwv[6] = {wb.z, wb.w, wc.x, wc.y, wc.z, wc.w};
  int   ihv[6] = {ia.x, ia.y, ia.z, ia.w, ib.x, ib.y};
  int   iwv[6] = {ib.z, ib.w, ic.x, ic.y, ic.z, ic.w};
  const uint32_t* g = G + (size_t)i * NK * NK;
  // all 36 offsets, then all 36 loads in flight, then reduce
  int offs[36];
#pragma unroll
  for (int jw = 0; jw < 6; jw++) {
    int cb = iwv[jw] * NK;
#pragma unroll
    for (int jh = 0; jh < 6; jh++) offs[jw * 6 + jh] = cb + ihv[jh];
  }
  uint32_t raw[36];
#pragma unroll
  for (int t = 0; t < 36; t++) raw[t] = g[offs[t]];
  __builtin_amdgcn_sched_barrier(0);   // don't sink loads into the FMA chain
  float ar = 0.f, ai = 0.f;
#pragma unroll
  for (int jw = 0; jw < 6; jw++) {
    float sr = 0.f, si = 0.f;
#pragma unroll
    for (int jh = 0; jh < 6; jh++) {
      float2 v = h2_to_f2(raw[jw * 6 + jh]);
      sr = fmaf(whv[jh], v.x, sr);
      si = fmaf(whv[jh], v.y, si);
    }
    ar = fmaf(wwv[jw], sr, ar);
    ai = fmaf(wwv[jw], si, ai);
  }
  float c = wd.x, s = wd.y;
  size_t o = (size_t)(p * NIMG + i) * KLEN + l;
  ((float2*)out)[o] = make_float2(ar * c - ai * s, ar * s + ai * c);
}

extern "C" void kernel_launch(void* const* d_in, const int* in_sizes, int n_in,
                              void* d_out, int out_size, void* d_ws, size_t ws_size,
                              hipStream_t stream) {
  const float* img  = (const float*)d_in[0];   // (1,5,8,2,320,320,2) f32
  const float* traj = (const float*)d_in[1];   // (5,2,16000) f32
  float* out = (float*)d_out;                  // (1,5,8,2,16000,2) f32

  char* ws = (char*)d_ws;
  float*    tapw = (float*)ws;                       // 5*16000*16*4 = 5,120,000 B
  int*      tapi = (int*)(ws + 5120000);             // 5*16000*12*4 = 3,840,000 B
  uint32_t* AT   = (uint32_t*)(ws + 8960000);        // 80*640*320*4 = 65,536,000 B (fp16)
  const size_t Goff = 8960000 + 65536000;            // 74,496,000
  const size_t Gb   = (size_t)NIMG * NK * NK * 4;    // 26,214,400 B (fp16)
  // per-phase G buffers if workspace allows (removes cross-phase RAW on G);
  // branch depends only on ws_size -> identical work every call (graph-safe)
  size_t Gstride = (ws_size >= Goff + 5 * Gb) ? Gb : 0;

  taps_kernel<<<(NPH * KLEN + 255) / 256, 256, 0, stream>>>(traj, tapw, tapi);
  stageA_kernel<<<NPH * NIMG * 20, 256, 0, stream>>>(img, AT);
  for (int p = 0; p < NPH; p++) {
    uint32_t* Gp = (uint32_t*)(ws + Goff + (size_t)p * Gstride);
    stageB_kernel<<<NIMG * 160, 256, 0, stream>>>(AT, Gp, p);
    interp_kernel<<<2000, 128, 0, stream>>>(Gp, tapw, tapi, out, p);
  }
}

// Round 10
// 300.419 us; speedup vs baseline: 3.0420x; 1.2017x over previous
//
#include <hip/hip_runtime.h>
#include <hip/hip_fp16.h>
#include <cstdint>
#include <cstddef>

// NUFFT type-2, torchkbnufft-compatible (J=6, alpha=14.04, os=2).
// Pipeline (5 phases, 16 coil-images each, 320x320 -> 640x640):
//   taps:   KB weights + [kh_base, 6 wrapped kw indices] per (phase,point)
//   stageA: ALL phases, apodize+pad rows, reg-FFT-640 along W -> AT[pi][kw][h] fp16.
//           512-thread blocks: 16 rows/block, 8 waves x 2 FFTs (R8-proven shape;
//           its replay failure was the NT hints, now removed). LDS stride 709
//           (>=703 needed by 11*k2+k1 layout). Transposed write: 16 consecutive
//           h per kw = full 64B lines.
//   per phase p:
//     stageB: reg-FFT-640 along H -> G_p[i][kw][kh] fp16, rows PADDED to 648
//             with kh 0..5 duplicated at 640..645 (k2==0 lane writes them), so
//             interp needs no mod-wrap. XCD-PINNED per image (i on XCD i%8).
//     interp: 6 columns x 4 uint2 loads (taps are 6 CONSECUTIVE padded kh) =
//             24 aligned 8B loads/point vs 36 scalar gathers. Same XCD pinning;
//             sched_barrier(0) keeps all loads in flight.
// FFT-640 = four-step 10x64 in registers: zero-padded FFT-10 (2x FFT-5), twiddle,
// 6 __shfl_xor butterfly stages with sign-fold + lane-conditional twiddle.
// fp16 storage: rel err ~5e-4 << 4.06e-2 threshold (measured absmax 0.0078).

#define PI_F     3.14159265358979323846f
#define KB_ALPHA 14.04f
#define NPH  5
#define NIMG 16
#define NH   320
#define NK   640
#define NKP  648   // padded G row stride (uint32 elems); 640..645 mirror 0..5
#define KLEN 16000

__device__ __forceinline__ uint32_t f2_to_h2(float2 v) {
  union { __half2 h; uint32_t u; } cv;
  cv.h = __float22half2_rn(v);
  return cv.u;
}
__device__ __forceinline__ float2 h2_to_f2(uint32_t u) {
  union { uint32_t u; __half2 h; } cv;
  cv.u = u;
  return __half22float2(cv.h);
}

// ---- modified Bessel I0 (A&S 9.8.1 / 9.8.2, rel err ~2e-7). I0(alpha) cancels
// between apodization (numerator) and tap weights (denominator). ----
__device__ __forceinline__ float i0f(float x) {
  if (x < 3.75f) {
    float t = x * (1.0f / 3.75f), t2 = t * t;
    return 1.0f + t2 * (3.5156229f + t2 * (3.0899424f + t2 * (1.2067492f +
                 t2 * (0.2659732f + t2 * (0.0360768f + t2 * 0.0045813f)))));
  }
  float t = 3.75f / x;
  float poly = 0.39894228f + t * (0.01328592f + t * (0.00225319f + t * (-0.00157565f +
               t * (0.00916281f + t * (-0.02057706f + t * (0.02635537f +
               t * (-0.01647633f + t * 0.00392377f)))))));
  return expf(x) * rsqrtf(x) * poly;
}

// apodization scale (1/FT(KB)); z^2 = alpha^2-(pi*J*u)^2 > 0 always for |u|<=0.25
__device__ __forceinline__ float apodf(int n) {
  float u = (float)(n - 160) * (1.0f / 640.0f);
  float pj = PI_F * 6.0f * u;
  float z = sqrtf(KB_ALPHA * KB_ALPHA - pj * pj);
  float sh = 0.5f * (expf(z) - expf(-z));     // sinh(z)
  return z * i0f(KB_ALPHA) / (6.0f * sh);     // 1/ft = z*I0a/(J*sinh z)
}

__device__ __forceinline__ float2 cadd(float2 a, float2 b) { return make_float2(a.x + b.x, a.y + b.y); }
__device__ __forceinline__ float2 cmul(float2 a, float2 b) {
  return make_float2(fmaf(a.x, b.x, -a.y * b.y), fmaf(a.x, b.y, a.y * b.x));
}
__device__ __forceinline__ float2 cxmad(float2 a, float2 w, float2 x) {
  a.x = fmaf(w.x, x.x, fmaf(-w.y, x.y, a.x));
  a.y = fmaf(w.x, x.y, fmaf( w.y, x.x, a.y));
  return a;
}

// direct 5-point DFT, forward (W5 = e^{-2pi i/5})
__device__ __forceinline__ void fft5(const float2 b[5], float2 z[5]) {
  const float2 w1 = make_float2( 0.309016994374947424f, -0.951056516295153572f);
  const float2 w2 = make_float2(-0.809016994374947424f, -0.587785252292473129f);
  const float2 w3 = make_float2(-0.809016994374947424f,  0.587785252292473129f);
  const float2 w4 = make_float2( 0.309016994374947424f,  0.951056516295153572f);
  z[0] = cadd(cadd(b[0], b[1]), cadd(cadd(b[2], b[3]), b[4]));
  z[1] = b[0]; z[1] = cxmad(z[1], w1, b[1]); z[1] = cxmad(z[1], w2, b[2]); z[1] = cxmad(z[1], w3, b[3]); z[1] = cxmad(z[1], w4, b[4]);
  z[2] = b[0]; z[2] = cxmad(z[2], w2, b[1]); z[2] = cxmad(z[2], w4, b[2]); z[2] = cxmad(z[2], w1, b[3]); z[2] = cxmad(z[2], w3, b[4]);
  z[3] = b[0]; z[3] = cxmad(z[3], w3, b[1]); z[3] = cxmad(z[3], w1, b[2]); z[3] = cxmad(z[3], w4, b[3]); z[3] = cxmad(z[3], w2, b[4]);
  z[4] = b[0]; z[4] = cxmad(z[4], w4, b[1]); z[4] = cxmad(z[4], w3, b[2]); z[4] = cxmad(z[4], w2, b[3]); z[4] = cxmad(z[4], w1, b[4]);
}

// Register FFT-640 of the zero-padded sequence x[64*n1 + lane] = b[n1] (n1=0..4;
// n1=5..9 implicitly zero). Returns k2 = bitrev6(lane); v[k1] = X[k1 + 10*k2].
__device__ __forceinline__ int fft640_reg(const float2 b[5], float2 v[10], int lane) {
  // FFT-10 with upper half zero: even outputs FFT5(b), odd outputs FFT5(b .* W10^n)
  const float2 t1 = make_float2( 0.809016994374947424f, -0.587785252292473129f); // W10^1
  const float2 t2 = make_float2( 0.309016994374947424f, -0.951056516295153572f); // W10^2
  const float2 t3 = make_float2(-0.309016994374947424f, -0.951056516295153572f); // W10^3
  const float2 t4 = make_float2(-0.809016994374947424f, -0.587785252292473129f); // W10^4
  float2 e[5], o[5], bp[5];
  fft5(b, e);
  bp[0] = b[0]; bp[1] = cmul(b[1], t1); bp[2] = cmul(b[2], t2);
  bp[3] = cmul(b[3], t3); bp[4] = cmul(b[4], t4);
  fft5(bp, o);
  v[0] = e[0]; v[2] = e[1]; v[4] = e[2]; v[6] = e[3]; v[8] = e[4];
  v[1] = o[0]; v[3] = o[1]; v[5] = o[2]; v[7] = o[3]; v[9] = o[4];
  // twiddle: v[k1] *= W640^{lane*k1}
  float sn, cs;
  __sincosf(-2.0f * PI_F * (float)lane * (1.0f / 640.0f), &sn, &cs);
  float2 w1 = make_float2(cs, sn), wk = w1;
  v[1] = cmul(v[1], wk);
#pragma unroll
  for (int k = 2; k < 10; k++) { wk = cmul(wk, w1); v[k] = cmul(v[k], wk); }
  // cross-lane FFT-64 over n2=lane: DIF radix-2, 6 shuffle stages, bitrev output.
  // Butterfly: t = sgn*v + oth, then *twl (stage twiddle on upper lanes, exact
  // identity (1,0) on lower lanes).
#pragma unroll
  for (int s = 5; s >= 1; s--) {
    int half = 1 << s;
    int up = lane & half;
    float ang = -(PI_F / (float)half) * (float)(lane & (half - 1));
    float ss, cc;
    __sincosf(ang, &ss, &cc);
    float sgn = up ? -1.0f : 1.0f;
    float2 twl = make_float2(up ? cc : 1.0f, up ? ss : 0.0f);
#pragma unroll
    for (int q = 0; q < 10; q++) {
      float2 oth;
      oth.x = __shfl_xor(v[q].x, half, 64);
      oth.y = __shfl_xor(v[q].y, half, 64);
      float2 t = make_float2(fmaf(sgn, v[q].x, oth.x), fmaf(sgn, v[q].y, oth.y));
      v[q] = cmul(t, twl);
    }
  }
  {  // final stage half=1: twiddle is identity everywhere — adds/subs only
    float sgn = (lane & 1) ? -1.0f : 1.0f;
#pragma unroll
    for (int q = 0; q < 10; q++) {
      float2 oth;
      oth.x = __shfl_xor(v[q].x, 1, 64);
      oth.y = __shfl_xor(v[q].y, 1, 64);
      v[q] = make_float2(fmaf(sgn, v[q].x, oth.x), fmaf(sgn, v[q].y, oth.y));
    }
  }
  return __brev(lane) >> 26;
}

// ---- stage A: ALL phases. 16 rows/block; 8 waves x 2 sequential row-FFTs,
// fp16 LDS staging (stride 709 >= 703 required by 11*k2+k1 layout),
// transposed write = full 64B lines. grid = 5*16*20 = 1600 blocks x 512 ----
#define ASTR 709
__global__ __launch_bounds__(512) void stageA_kernel(const float* __restrict__ img,
                                                     uint32_t* __restrict__ AT) {
  __shared__ uint32_t lds[16 * ASTR];   // 45,376 B fp16-pairs
  int wv = threadIdx.x >> 6, lane = threadIdx.x & 63;
  int bx = blockIdx.x;
  int p = bx / (NIMG * 20);
  int rem = bx - p * (NIMG * 20);
  int i = rem / 20, hg = rem - i * 20;
  int h0 = hg * 16;
  const float2* base = (const float2*)img + (size_t)(p * NIMG + i) * NH * NH;
  // w-apodization is row-invariant: compute the 5 lane scales once
  float aw[5];
#pragma unroll
  for (int j = 0; j < 5; j++) aw[j] = apodf(lane + 64 * j) * (1.0f / 640.0f);
  // 2 sequential row FFTs per wave: rows r = wv*2 + t
#pragma unroll 1
  for (int t = 0; t < 2; t++) {
    int r = wv * 2 + t;
    int h = h0 + r;
    const float2* src = base + (size_t)h * NH;
    float ah = apodf(h);
    float2 b[5];
#pragma unroll
    for (int j = 0; j < 5; j++) {
      float2 x = src[lane + 64 * j];
      float sc = aw[j] * ah;
      b[j] = make_float2(x.x * sc, x.y * sc);
    }
    float2 v[10];
    int k2 = fft640_reg(b, v, lane);
    uint32_t* rowl = lds + r * ASTR + 11 * k2;   // kw=k1+10*k2 at 11*k2+k1 (max 702 < 709)
#pragma unroll
    for (int k = 0; k < 10; k++) rowl[k] = f2_to_h2(v[k]);
  }
  __syncthreads();
  // transposed write: AT[kw][h0+c], c = tid&15 -> 16 consecutive h = 64B line
  int c = threadIdx.x & 15, kwv = threadIdx.x >> 4;   // kwv in [0,32)
  uint32_t* dst = AT + (size_t)(p * NIMG + i) * NK * NH + h0 + c;
  const uint32_t* srcl = lds + c * ASTR;
#pragma unroll
  for (int s = 0; s < 20; s++) {
    int kw = kwv + 32 * s;
    int q2 = (kw * 6554) >> 16;     // kw/10 (exact for kw<1638)
    int q1 = kw - 10 * q2;
    dst[(size_t)kw * NH] = srcl[11 * q2 + q1];
  }
}

// ---- stage B: column FFTs, pure-register, XCD-PINNED per image, padded rows.
// grid = 2560 blocks x 256 per phase; bx = 8*J + x, x = XCD = i%8;
// J<160 -> image x, J>=160 -> image x+8. k2==0 lane mirrors kh 0..5 -> 640..645. ----
__global__ __launch_bounds__(256) void stageB_kernel(const uint32_t* __restrict__ AT,
                                                     uint32_t* __restrict__ G, int p) {
  int wv = threadIdx.x >> 6, lane = threadIdx.x & 63;
  int x = blockIdx.x & 7;
  int J = blockIdx.x >> 3;           // 0..319
  int i = x + 8 * (J >= 160);
  int kwg = (J >= 160) ? J - 160 : J;
  int kw = kwg * 4 + wv;
  const uint32_t* rowp = AT + ((size_t)(p * NIMG + i) * NK + kw) * NH;  // contiguous
  float2 b[5];
#pragma unroll
  for (int j = 0; j < 5; j++) b[j] = h2_to_f2(rowp[lane + 64 * j]);
  float2 v[10];
  int k2 = fft640_reg(b, v, lane);
  // lane writes 10 consecutive kh as 5 uint2 (pairs of half2); stays in L2
  uint32_t hv[10];
#pragma unroll
  for (int k = 0; k < 10; k++) hv[k] = f2_to_h2(v[k]);
  uint32_t* rowo = G + ((size_t)i * NK + kw) * NKP;
  uint2* dst = (uint2*)(rowo + 10 * k2);
#pragma unroll
  for (int m = 0; m < 5; m++) dst[m] = make_uint2(hv[2 * m], hv[2 * m + 1]);
  if (k2 == 0) {                     // mirror kh 0..5 at 640..645 (pad, no wrap in interp)
    uint2* pd = (uint2*)(rowo + 640);
#pragma unroll
    for (int m = 0; m < 3; m++) pd[m] = make_uint2(hv[2 * m], hv[2 * m + 1]);
  }
}

// ---- taps: per (phase, point): kh weights[6], kw weights[6], phase (c,s) in tapw
// (stride 16 floats); [kh_base, kw_idx[6], pad] in tapi (stride 8 ints, int4x2) ----
__global__ __launch_bounds__(256) void taps_kernel(const float* __restrict__ traj,
                                                   float* __restrict__ tapw,
                                                   int* __restrict__ tapi) {
  int t = blockIdx.x * 256 + threadIdx.x;
  if (t >= NPH * KLEN) return;
  int p = t / KLEN, l = t - p * KLEN;
  float inv_i0a = 1.0f / i0f(KB_ALPHA);
  float* wout = tapw + (size_t)t * 16;
  int* iout = tapi + (size_t)t * 8;
  float ang = 0.0f;
#pragma unroll
  for (int d = 0; d < 2; d++) {
    float om = traj[((size_t)p * 2 + d) * KLEN + l];
    float tt = om * 640.0f / 6.28318530717958647692f;
    float base = floorf(tt - 3.0f);
    ang += om * 160.0f;              // n_shift = 320//2
    if (d == 0) {                    // kh: store base index only (taps consecutive)
      int bi = (int)base + 1 + 640;  // [318, 958]
      if (bi >= 640) bi -= 640;      // [0, 639]
      iout[0] = bi;
    }
#pragma unroll
    for (int j = 0; j < 6; j++) {
      float kf = base + (float)(j + 1);
      float u = tt - kf;
      float arg = fmaxf(1.0f - (u * u) * (1.0f / 9.0f), 0.0f);
      wout[d * 6 + j] = i0f(KB_ALPHA * sqrtf(arg)) * inv_i0a;
      if (d == 1) {                  // kw: individually wrapped indices
        int ki = (int)kf + 640;
        if (ki >= 640) ki -= 640;
        iout[1 + j] = ki;
      }
    }
  }
  float s, c;
  sincosf(ang, &s, &c);              // accurate path: |ang| up to ~1005 rad
  wout[12] = c;
  wout[13] = s;
  wout[14] = 0.f;
  wout[15] = 0.f;
  iout[7] = 0;
}

// ---- interp: XCD-pinned gather from L2-hot padded fp16 G. 2000 blocks x 128.
// Per column: 4 aligned uint2 loads cover the 6 consecutive kh taps (window
// offset off = b0&1 folded into a 7-wide select-built weight vector). ----
__global__ __launch_bounds__(128) void interp_kernel(const uint32_t* __restrict__ G,
                                                     const float* __restrict__ tapw,
                                                     const int* __restrict__ tapi,
                                                     float* __restrict__ out, int p) {
  int x = blockIdx.x & 7;            // XCD (round-robin dispatch heuristic)
  int j = blockIdx.x >> 3;           // 0..249
  int i = x + 8 * (j >= 125);
  int jj = (j >= 125) ? j - 125 : j;
  int l = jj * 128 + threadIdx.x;
  // vectorized tap loads
  const float4* w4 = (const float4*)(tapw + (size_t)(p * KLEN + l) * 16);
  float4 wa = w4[0], wb = w4[1], wc = w4[2], wd = w4[3];
  const int4* i4 = (const int4*)(tapi + (size_t)(p * KLEN + l) * 8);
  int4 ia = i4[0], ib = i4[1];
  float whv[6] = {wa.x, wa.y, wa.z, wa.w, wb.x, wb.y};
  float wwv[6] = {wb.z, wb.w, wc.x, wc.y, wc.z, wc.w};
  int   iwv[6] = {ia.y, ia.z, ia.w, ib.x, ib.y, ib.z};
  int   b0 = ia.x;
  int   e = b0 & ~1, off = b0 & 1;
  // 7-wide shifted kh-weight window (off=0: w0..w5 at 0..5; off=1: at 1..6)
  float we[7];
  we[0] = off ? 0.f    : whv[0];
  we[1] = off ? whv[0] : whv[1];
  we[2] = off ? whv[1] : whv[2];
  we[3] = off ? whv[2] : whv[3];
  we[4] = off ? whv[3] : whv[4];
  we[5] = off ? whv[4] : whv[5];
  we[6] = off ? whv[5] : 0.f;
  const uint32_t* g = G + (size_t)i * (NK * NKP) + e;
  // all 24 loads in flight, then reduce
  uint2 raw[6][4];
#pragma unroll
  for (int jw = 0; jw < 6; jw++) {
    const uint2* col = (const uint2*)(g + iwv[jw] * NKP);
#pragma unroll
    for (int m = 0; m < 4; m++) raw[jw][m] = col[m];
  }
  __builtin_amdgcn_sched_barrier(0);   // don't sink loads into the FMA chain
  float ar = 0.f, ai = 0.f;
#pragma unroll
  for (int jw = 0; jw < 6; jw++) {
    float sr = 0.f, si = 0.f;
#pragma unroll
    for (int k = 0; k < 7; k++) {
      uint32_t u = (k & 1) ? raw[jw][k >> 1].y : raw[jw][k >> 1].x;
      float2 v = h2_to_f2(u);
      sr = fmaf(we[k], v.x, sr);
      si = fmaf(we[k], v.y, si);
    }
    ar = fmaf(wwv[jw], sr, ar);
    ai = fmaf(wwv[jw], si, ai);
  }
  float c = wd.x, s = wd.y;
  size_t o = (size_t)(p * NIMG + i) * KLEN + l;
  ((float2*)out)[o] = make_float2(ar * c - ai * s, ar * s + ai * c);
}

extern "C" void kernel_launch(void* const* d_in, const int* in_sizes, int n_in,
                              void* d_out, int out_size, void* d_ws, size_t ws_size,
                              hipStream_t stream) {
  const float* img  = (const float*)d_in[0];   // (1,5,8,2,320,320,2) f32
  const float* traj = (const float*)d_in[1];   // (5,2,16000) f32
  float* out = (float*)d_out;                  // (1,5,8,2,16000,2) f32

  char* ws = (char*)d_ws;
  float*    tapw = (float*)ws;                       // 5*16000*16*4 = 5,120,000 B
  int*      tapi = (int*)(ws + 5120000);             // 5*16000* 8*4 = 2,560,000 B
  uint32_t* AT   = (uint32_t*)(ws + 8960000);        // 80*640*320*4 = 65,536,000 B (fp16)
  const size_t Goff = 8960000 + 65536000;            // 74,496,000
  const size_t Gb   = (size_t)NIMG * NK * NKP * 4;   // 26,542,080 B (fp16, padded rows)
  // per-phase G buffers if workspace allows (no cross-phase RAW on G);
  // branch depends only on ws_size -> identical work every call (graph-safe)
  size_t Gstride = (ws_size >= Goff + 5 * Gb) ? Gb : 0;

  taps_kernel<<<(NPH * KLEN + 255) / 256, 256, 0, stream>>>(traj, tapw, tapi);
  stageA_kernel<<<NPH * NIMG * 20, 512, 0, stream>>>(img, AT);
  for (int p = 0; p < NPH; p++) {
    uint32_t* Gp = (uint32_t*)(ws + Goff + (size_t)p * Gstride);
    stageB_kernel<<<NIMG * 160, 256, 0, stream>>>(AT, Gp, p);
    interp_kernel<<<2000, 128, 0, stream>>>(Gp, tapw, tapi, out, p);
  }
}